// Round 14
// baseline (143.776 us; speedup 1.0000x reference)
//
#include <hip/hip_runtime.h>
#include <stdint.h>

#define NGC 4096   // both node counts
#define FIN 512
#define DD  256

typedef __attribute__((ext_vector_type(8))) short short8;
typedef __attribute__((ext_vector_type(4))) float f32x4;
typedef unsigned short u16;
typedef unsigned int   u32;
typedef unsigned long long u64;

static __device__ __forceinline__ float bf2f(u16 u){ return __uint_as_float(((u32)u)<<16); }
static __device__ __forceinline__ u16 f2bf(float f){
  u32 u = __float_as_uint(f);
  u += 0x7fffu + ((u>>16)&1u);
  return (u16)(u>>16);
}
static __device__ __forceinline__ float lk(float x){ return fmaxf(x, 0.2f*x); }
static __device__ __forceinline__ u64 shfl_xor64(u64 x, int m){
  u32 lo = (u32)x, hi = (u32)(x >> 32);
  lo = __shfl_xor(lo, m); hi = __shfl_xor(hi, m);
  return ((u64)hi << 32) | lo;
}
// async global->LDS: lds dest = uniform base + lane*16; global src per-lane.
static __device__ __forceinline__ void gl16(const void* g, void* l){
  __builtin_amdgcn_global_load_lds(
    (const __attribute__((address_space(1))) void*)g,
    (__attribute__((address_space(3))) void*)l, 16, 0, 0);
}

// ---------------------------------------------------------------------------
// k_wcvt: W (f32) -> bf16 copies for the GEMM.
// ---------------------------------------------------------------------------
__global__ __launch_bounds__(256) void k_wcvt(
    const float* __restrict__ Wg, const float* __restrict__ Wc,
    u16* __restrict__ Wgbf, u16* __restrict__ Wcbf)
{
  int base = (blockIdx.x*256 + threadIdx.x)*4;   // grid 128 -> 131072 elems
  float4 a = *(const float4*)(Wg + base);
  float4 b = *(const float4*)(Wc + base);
  ushort4 oa, ob;
  oa.x=f2bf(a.x); oa.y=f2bf(a.y); oa.z=f2bf(a.z); oa.w=f2bf(a.w);
  ob.x=f2bf(b.x); ob.y=f2bf(b.y); ob.z=f2bf(b.z); ob.w=f2bf(b.w);
  *(ushort4*)(Wgbf + base) = oa;
  *(ushort4*)(Wcbf + base) = ob;
}

// ---------------------------------------------------------------------------
// k_pack: bit-pack 3 adjacency matrices (f32 0/1 -> 1 bit), PLAIN layout:
// bit k of row r at u64 word [r*64 + k/64]. One wave per row; lane l packs
// ITS OWN 64 consecutive elements (16 independent float4 loads, no cross-
// lane ops, no LDS) -> one u64 -> contiguous 512B store per wave.
// r13's shuffle-tree version was latency-starved (VGPR=24 -> 1-2 loads in
// flight); independent per-lane loads restore MLP.
// ---------------------------------------------------------------------------
__global__ __launch_bounds__(256) void k_pack(
    const float* __restrict__ gene_adj, const float* __restrict__ cell_adj,
    const float* __restrict__ gc_adj,   u64* __restrict__ packbits)
{
  int t = threadIdx.x, wid = t>>6, lane = t&63;
  int gw = blockIdx.x*4 + wid;          // 0..12287
  int mat = gw >> 12;
  int row = gw & 4095;
  const float* src = (mat==0) ? gene_adj : (mat==1) ? cell_adj : gc_adj;
  const float* rp = src + (size_t)row*NGC + lane*64;

  float4 v[16];
  #pragma unroll
  for(int j = 0; j < 16; j++)
    v[j] = *(const float4*)(rp + j*4);

  u64 w = 0;
  #pragma unroll
  for(int j = 0; j < 16; j++){
    u32 nib = (v[j].x!=0.f?1u:0u) | (v[j].y!=0.f?2u:0u)
            | (v[j].z!=0.f?4u:0u) | (v[j].w!=0.f?8u:0u);
    w |= ((u64)nib) << (j*4);
  }
  packbits[((size_t)mat << 18) + (size_t)row*64 + lane] = w;
}

// ---------------------------------------------------------------------------
// k_bitTT: transpose gc bits -> bitsT (both PLAIN layout, u64 load/store).
// One wave per 64x64-bit tile; 4096 tiles; 4 waves/block -> 1024 blocks.
// ---------------------------------------------------------------------------
__global__ __launch_bounds__(256) void k_bitTT(
    const u64* __restrict__ gcb, u64* __restrict__ bT)
{
  int t = threadIdx.x, wid = t>>6, lane = t&63;
  int id = blockIdx.x*4 + wid;          // 0..4095
  int G = id & 63, C = id >> 6;

  u64 x = gcb[(size_t)(64*G + lane)*64 + C];

  const u64 M1  = 0xAAAAAAAAAAAAAAAAull;
  const u64 M2  = 0xCCCCCCCCCCCCCCCCull;
  const u64 M4  = 0xF0F0F0F0F0F0F0F0ull;
  const u64 M8  = 0xFF00FF00FF00FF00ull;
  const u64 M16 = 0xFFFF0000FFFF0000ull;
  const u64 M32 = 0xFFFFFFFF00000000ull;
  #define TSTEP(S, M) { u64 y = shfl_xor64(x, S); \
    x = (lane & S) ? ((x & (M)) | ((y >> S) & ~(M))) \
                   : ((x & ~(M)) | ((y << S) & (M))); }
  TSTEP(32, M32) TSTEP(16, M16) TSTEP(8, M8)
  TSTEP(4,  M4)  TSTEP(2,  M2)  TSTEP(1, M1)
  #undef TSTEP

  bT[(size_t)(64*C + lane)*64 + G] = x;
}

// ---------------------------------------------------------------------------
// k_hgemm: h = x @ W.T  (f32 x in -> bf16 staged, f32 h out + TILED bf16 hT)
// hTt layout: [kblock=k/32][dtile=d/16][kgrp=(k&31)/8][drow=d&15][k&7] so one
// MFMA A-fragment (16 d x 32 k = 1KB) is contiguous IN LANE-READ ORDER:
// lane (lrow,lhi) reads 16B at byte lhi*256+lrow*16 = lane*16.
// grid (64 row-tiles, 2 sides), 512 threads (8 waves). BM=64, BK=64, N=256.
// ---------------------------------------------------------------------------
__global__ __launch_bounds__(512) void k_hgemm(
    const float* __restrict__ xg, const float* __restrict__ xc,
    const u16* __restrict__ Wg, const u16* __restrict__ Wc,
    float* __restrict__ hg, float* __restrict__ hc,
    u16* __restrict__ hTg, u16* __restrict__ hTc)
{
  const int side = blockIdx.y;
  const float* x = side ? xc : xg;
  const u16* W = side ? Wc : Wg;
  float* h  = side ? hc : hg;
  u16*  hT  = side ? hTc : hTg;
  const int r0 = blockIdx.x * 64;
  const int t = threadIdx.x;
  const int wid = t >> 6, lane = t & 63;
  const int lrow = lane & 15, lhi = lane >> 4;

  __shared__ __align__(16) char smem[32768];

  f32x4 acc[4][2];
  const f32x4 z4 = {0.f,0.f,0.f,0.f};
  #pragma unroll
  for(int i=0;i<4;i++){ acc[i][0]=z4; acc[i][1]=z4; }

  const int r = t >> 3, c8 = t & 7;
  for(int k0 = 0; k0 < FIN; k0 += 64){
    const float* xp = x + (size_t)(r0 + r)*FIN + k0 + c8*8;
    float4 xa = *(const float4*)xp;
    float4 xb = *(const float4*)(xp + 4);
    short8 xv;
    xv[0]=(short)f2bf(xa.x); xv[1]=(short)f2bf(xa.y);
    xv[2]=(short)f2bf(xa.z); xv[3]=(short)f2bf(xa.w);
    xv[4]=(short)f2bf(xb.x); xv[5]=(short)f2bf(xb.y);
    xv[6]=(short)f2bf(xb.z); xv[7]=(short)f2bf(xb.w);
    int wbyte = r*128 + (((c8 ^ (r & 7)) & 7) << 4);
    *(short8*)(smem + wbyte) = xv;
    __syncthreads();
    #pragma unroll
    for(int ksub = 0; ksub < 2; ksub++){
      short8 b[2];
      #pragma unroll
      for(int nf=0; nf<2; nf++){
        int n = wid*32 + nf*16 + lrow;
        b[nf] = *(const short8*)(W + (size_t)n*FIN + k0 + ksub*32 + lhi*8);
      }
      #pragma unroll
      for(int mf=0; mf<4; mf++){
        int row = mf*16 + lrow;
        int g = ksub*4 + lhi;
        short8 a = *(const short8*)(smem + row*128 + (((g ^ (row & 7)) & 7) << 4));
        #pragma unroll
        for(int nf=0; nf<2; nf++)
          acc[mf][nf] = __builtin_amdgcn_mfma_f32_16x16x32_bf16(a, b[nf], acc[mf][nf], 0,0,0);
      }
    }
    __syncthreads();
  }
  // write h (f32) and stage bf16 transpose in LDS
  #pragma unroll
  for(int mf=0; mf<4; mf++){
    #pragma unroll
    for(int nf=0; nf<2; nf++){
      int col = wid*32 + nf*16 + lrow;
      #pragma unroll
      for(int j=0;j<4;j++){
        int row = mf*16 + lhi*4 + j;
        float v = acc[mf][nf][j];
        h[(size_t)(r0+row)*DD + col] = v;
        int byte_ = col*128 + (((row*2) ^ ((col & 7)<<4)));
        *(u16*)(smem + byte_) = f2bf(v);
      }
    }
  }
  __syncthreads();
  { // tiled hT store (read-order layout): thread -> (n = t>>1 d-row, half)
    int n = t >> 1, half = t & 1;
    #pragma unroll
    for(int gi=0; gi<4; gi++){
      int g = half*4 + gi;
      int byte_ = n*128 + (((g ^ (n & 7)) & 7) << 4);
      short8 v = *(const short8*)(smem + byte_);
      int kcol = r0 + g*8;   // global k (node) index, 8-aligned
      size_t off = (size_t)(kcol>>5)*8192 + (size_t)(n>>4)*512
                 + ((kcol>>3)&3)*128 + (n&15)*8;
      *(short8*)(hT + off) = v;
    }
  }
}

// ---------------------------------------------------------------------------
// k_svec: per-row dot products with attention vectors + gate sigmoid.
// sbuf layout (each 4096 f32):
// 0 s1gg 1 s2gg 2 s1gc 3 s2cg 4 gam_g 5 s1cc 6 s2cc 7 s2gc 8 s1cg 9 gam_c
// ---------------------------------------------------------------------------
__global__ __launch_bounds__(256) void k_svec(
    const float* __restrict__ hg, const float* __restrict__ hc,
    const float* __restrict__ a_gg, const float* __restrict__ a_gc,
    const float* __restrict__ a_cc, const float* __restrict__ a_cg,
    const float* __restrict__ gw_g, const float* __restrict__ gb_g,
    const float* __restrict__ gw_c, const float* __restrict__ gb_c,
    float* __restrict__ sbuf)
{
  int t = threadIdx.x, wid = t>>6, lane = t&63;
  int idx = blockIdx.x * 4 + wid;          // 0..8191
  int side = idx >> 12;
  int row  = idx & 4095;
  const float* h = (side ? hc : hg) + (size_t)row*DD;
  const float* v0 = (side ? a_cc : a_gg);        // same-type s1 half
  const float* v1 = (side ? a_cc : a_gg) + DD;   // same-type s2 half
  const float* v2 = (side ? a_cg : a_gc);        // cross s1 (this node as src)
  const float* v3 = (side ? a_gc : a_cg) + DD;   // cross s2 (this node as dst)
  const float* gw = side ? gw_c : gw_g;
  float bias = (side ? gb_c : gb_g)[0];

  float4 hv = *(const float4*)(h + lane*4);
  float4 w0 = *(const float4*)(v0 + lane*4);
  float4 w1 = *(const float4*)(v1 + lane*4);
  float4 w2 = *(const float4*)(v2 + lane*4);
  float4 w3 = *(const float4*)(v3 + lane*4);
  float4 w4 = *(const float4*)(gw + lane*4);

  float d0 = hv.x*w0.x + hv.y*w0.y + hv.z*w0.z + hv.w*w0.w;
  float d1 = hv.x*w1.x + hv.y*w1.y + hv.z*w1.z + hv.w*w1.w;
  float d2 = hv.x*w2.x + hv.y*w2.y + hv.z*w2.z + hv.w*w2.w;
  float d3 = hv.x*w3.x + hv.y*w3.y + hv.z*w3.z + hv.w*w3.w;
  float d4 = hv.x*w4.x + hv.y*w4.y + hv.z*w4.z + hv.w*w4.w;
  #pragma unroll
  for(int s=1;s<64;s<<=1){
    d0 += __shfl_xor(d0, s); d1 += __shfl_xor(d1, s); d2 += __shfl_xor(d2, s);
    d3 += __shfl_xor(d3, s); d4 += __shfl_xor(d4, s);
  }
  if(lane == 0){
    float gam = 1.f/(1.f + __expf(-(d4 + bias)));
    if(side == 0){
      sbuf[0*4096+row]=d0; sbuf[1*4096+row]=d1; sbuf[2*4096+row]=d2;
      sbuf[3*4096+row]=d3; sbuf[4*4096+row]=gam;
    } else {
      sbuf[5*4096+row]=d0; sbuf[6*4096+row]=d1; sbuf[8*4096+row]=d2;
      sbuf[7*4096+row]=d3; sbuf[9*4096+row]=gam;
    }
  }
}

// ---------------------------------------------------------------------------
// k_gat: O^T = V^T * P^T, P generated in-register as the MFMA B-operand.
// grid (64 ng, 2 kc, 4 modes) x 256 thr (4 waves: 2 kh x 2 ng).
// A staged in LDS (global_load_lds, double-buffered, 32KB/step) and SHARED
// by the ng waves; conflict-free ds_read_b128 (fragment in lane-read order).
// One barrier/step; staging issued at step top so exp+MFMA hides L2 latency.
// Masks in XOR-swizzled LDS; s2 register-prefetched. 80KB LDS -> 2 blocks/CU.
// ---------------------------------------------------------------------------
__global__ __launch_bounds__(256,2) void k_gat(
    const float* __restrict__ sbuf,
    const uint8_t* __restrict__ packbits, const uint8_t* __restrict__ bitsT,
    const u16* __restrict__ hTg, const u16* __restrict__ hTc,
    float* __restrict__ part, float* __restrict__ Zpart)
{
  const int mode = blockIdx.z;
  const int kc   = blockIdx.y;
  const int nodebase = blockIdx.x * 64;
  const int kcbase   = kc * 2048;

  const float* s1; const float* s2; const uint8_t* bits; const u16* hT;
  if(mode == 0){ s1 = sbuf;        s2 = sbuf+4096;   bits = packbits;           hT = hTg; }
  else if(mode == 1){ s1 = sbuf+2*4096; s2 = sbuf+7*4096; bits = packbits+4194304; hT = hTc; }
  else if(mode == 2){ s1 = sbuf+5*4096; s2 = sbuf+6*4096; bits = packbits+2097152; hT = hTc; }
  else { s1 = sbuf+8*4096; s2 = sbuf+3*4096; bits = bitsT; hT = hTg; }

  const int t = threadIdx.x, wid = t>>6, lane = t&63, lrow = lane&15, lhi = lane>>4;
  const int kh = wid >> 1;        // k-half of the 2048 chunk
  const int ng_sub = wid & 1;     // 32-node group

  __shared__ __align__(16) char U[81920];
  char* A_lds  = U;               // [2 dbuf][2 kh][16KB]
  char* mask_l = U + 65536;       // [64 rows][256B], 16B-slot XOR-swizzled

  // ---- prologue: stage masks (16KB, swizzled 16B slots) ----
  {
    int row = t>>2, seg = t&3;
    const char* g = (const char*)bits + (size_t)(nodebase+row)*512 + kc*256 + seg*64;
    char* drow_ = mask_l + row*256;
    #pragma unroll
    for(int i=0;i<4;i++){
      int slot = seg*4 + i;
      *(ulonglong2*)(drow_ + (((slot ^ (row&7)))<<4)) = *(const ulonglong2*)(g + i*16);
    }
  }
  // ---- prologue: stage A step 0 into buf0 (each wave: its kh, its half) ----
  const char* hTb = (const char*)hT;
  {
    const char* g = hTb + ((size_t)kc*64 + kh*32 + 0)*16384 + ng_sub*8192 + lane*16;
    char* l = A_lds + 0*32768 + kh*16384 + ng_sub*8192;
    #pragma unroll
    for(int i=0;i<8;i++) gl16(g + i*1024, l + i*1024);
  }
  // ---- per-wave global max over FULL s2 (no cross-wave reduce needed) ----
  float mxv = -1e30f;
  #pragma unroll
  for(int i=0;i<16;i++){
    float4 v = *(const float4*)(s2 + lane*64 + i*4);
    mxv = fmaxf(mxv, fmaxf(fmaxf(v.x,v.y), fmaxf(v.z,v.w)));
  }
  #pragma unroll
  for(int sh=1; sh<64; sh<<=1) mxv = fmaxf(mxv, __shfl_xor(mxv, sh));
  const float maxs2 = mxv;

  const int wnode = nodebase + ng_sub*32;
  const float L2E = 1.4426950408889634f;
  float c1[2], c2[2], z[2];
  #pragma unroll
  for(int nf=0; nf<2; nf++){
    float s1v = s1[wnode + nf*16 + lrow];
    float m = lk(s1v + maxs2);
    c1[nf] = (s1v - m)*L2E;
    c2[nf] = (0.2f*s1v - m)*L2E;
    z[nf] = 0.f;
  }

  f32x4 acc[16][2];
  const f32x4 zz = {0.f,0.f,0.f,0.f};
  #pragma unroll
  for(int i=0;i<16;i++){ acc[i][0]=zz; acc[i][1]=zz; }

  const float* s2g = s2 + kcbase + kh*1024 + lhi*8;
  const char* mrow0 = mask_l + (ng_sub*32 + lrow)*256;
  const char* mrow1 = mask_l + (ng_sub*32 + 16 + lrow)*256;
  const int mx0 = (ng_sub*32 + lrow) & 7, mx1 = (ng_sub*32 + 16 + lrow) & 7;

  // s2 register prefetch for step 0
  float4 csA = *(const float4*)(s2g);
  float4 csB = *(const float4*)(s2g + 4);

  __syncthreads();   // masks + A step0 staged (vmcnt drained)

  // ---- main loop: 32 steps, 1 barrier/step ----
  #pragma unroll 1
  for(int s=0; s<32; s++){
    const int cur = s & 1;
    // stage step s+1 into buf^1 (hidden under this step's compute)
    if(s < 31){
      const char* g = hTb + ((size_t)kc*64 + kh*32 + s + 1)*16384 + ng_sub*8192 + lane*16;
      char* l = A_lds + (cur^1)*32768 + kh*16384 + ng_sub*8192;
      #pragma unroll
      for(int i=0;i<8;i++) gl16(g + i*1024, l + i*1024);
    }
    float4 sA = csA, sB = csB;
    if(s < 31){
      csA = *(const float4*)(s2g + (s+1)*32);
      csB = *(const float4*)(s2g + (s+1)*32 + 4);
    }
    float e1[8], e2[8];
    {
      float sv[8] = {sA.x,sA.y,sA.z,sA.w,sB.x,sB.y,sB.z,sB.w};
      #pragma unroll
      for(int j=0;j<8;j++){ e1[j] = sv[j]*L2E; e2[j] = sv[j]*(0.2f*L2E); }
    }
    // mask words (swizzled slot): wb = kh*128 + s*4
    const int slot = kh*8 + (s>>2), win = (s&3)*4;
    u32 mw0 = *(const u32*)(mrow0 + ((slot ^ mx0)<<4) + win);
    u32 mw1 = *(const u32*)(mrow1 + ((slot ^ mx1)<<4) + win);
    short8 b[2];
    #pragma unroll
    for(int nf=0; nf<2; nf++){
      u32 mw = nf ? mw1 : mw0;
      u32 w4[4];
      #pragma unroll
      for(int pr=0; pr<4; pr++){
        float bit0 = (float)((mw >> (lhi*8 + 2*pr  )) & 1u);
        float bit1 = (float)((mw >> (lhi*8 + 2*pr+1)) & 1u);
        float p0 = __builtin_amdgcn_exp2f(fmaxf(c1[nf]+e1[2*pr  ], c2[nf]+e2[2*pr  ])) * bit0;
        float p1 = __builtin_amdgcn_exp2f(fmaxf(c1[nf]+e1[2*pr+1], c2[nf]+e2[2*pr+1])) * bit1;
        z[nf] += p0 + p1;
        u32 q0 = __float_as_uint(p0) + 0x8000u;
        u32 q1 = __float_as_uint(p1) + 0x8000u;
        w4[pr] = (q1 & 0xFFFF0000u) | (q0 >> 16);
      }
      union{ u32 u[4]; short8 s8; } cv;
      cv.u[0]=w4[0]; cv.u[1]=w4[1]; cv.u[2]=w4[2]; cv.u[3]=w4[3];
      b[nf] = cv.s8;
    }
    // A from LDS (conflict-free: lane reads byte lane*16 of each 1KB frag)
    const char* Af = A_lds + cur*32768 + kh*16384 + lane*16;
    #pragma unroll
    for(int mf=0; mf<16; mf++){
      short8 a = *(const short8*)(Af + mf*1024);
      acc[mf][0] = __builtin_amdgcn_mfma_f32_16x16x32_bf16(a, b[0], acc[mf][0], 0,0,0);
      acc[mf][1] = __builtin_amdgcn_mfma_f32_16x16x32_bf16(a, b[1], acc[mf][1], 0,0,0);
    }
    __syncthreads();   // protects buf reuse + completes s+1 staging
  }

  // ---- Z: reduce across lhi, write per-(kc,kh) slot; k_epi sums 4 ----
  #pragma unroll
  for(int nf=0; nf<2; nf++){
    z[nf] += __shfl_xor(z[nf], 16);
    z[nf] += __shfl_xor(z[nf], 32);
  }
  if(lhi == 0){
    float* zp = Zpart + (size_t)(mode*4 + kc*2 + kh)*4096 + wnode;
    zp[lrow]      = z[0];
    zp[16 + lrow] = z[1];
  }

  // ---- kh-reduce via 32KB swizzled LDS (two 8-mf rounds), then store ----
  __syncthreads();                 // loop done; A_lds free
  float* R = (float*)A_lds;        // [64 rows][128 f32], XOR-swizzled
  float* po = part + ((size_t)(mode*2 + kc) << 20);
  #pragma unroll
  for(int half=0; half<2; half++){
    if(kh == 1){
      #pragma unroll
      for(int mf8=0; mf8<8; mf8++){
        #pragma unroll
        for(int nf=0; nf<2; nf++){
          int r = ng_sub*32 + nf*16 + lrow;
          int byte_ = r*512 + ((mf8*64 + lhi*16) ^ ((r&7)<<4));
          *(f32x4*)((char*)R + byte_) = acc[half*8 + mf8][nf];
        }
      }
    }
    __syncthreads();
    if(kh == 0){
      #pragma unroll
      for(int mf8=0; mf8<8; mf8++){
        #pragma unroll
        for(int nf=0; nf<2; nf++){
          int r = ng_sub*32 + nf*16 + lrow;
          int byte_ = r*512 + ((mf8*64 + lhi*16) ^ ((r&7)<<4));
          f32x4 o = *(const f32x4*)((const char*)R + byte_);
          o = o + acc[half*8 + mf8][nf];
          int node = nodebase + r;
          *(f32x4*)(po + (size_t)node*256 + (half*8+mf8)*16 + lhi*4) = o;
        }
      }
    }
    __syncthreads();
  }
}

// ---------------------------------------------------------------------------
// k_epi: out = leaky(h + sum(A)/za + gamma*sum(B)/zb), fused kc/kh-reduce.
// ---------------------------------------------------------------------------
__global__ __launch_bounds__(256) void k_epi(
    const float* __restrict__ hg, const float* __restrict__ hc,
    const float* __restrict__ part, const float* __restrict__ Zpart,
    const float* __restrict__ sbuf, float* __restrict__ out)
{
  int idx = blockIdx.x*256 + threadIdx.x;   // 0..524287
  int fid = idx*4;
  int side = fid >> 20;
  int l = fid & 1048575;
  int node = l >> 8;
  int modeA = side ? 2 : 0, modeB = side ? 3 : 1;
  const float* h = side ? hc : hg;
  float gam = sbuf[(side ? 9 : 4)*4096 + node];
  float za = Zpart[(size_t)(modeA*4+0)*4096 + node] + Zpart[(size_t)(modeA*4+1)*4096 + node]
           + Zpart[(size_t)(modeA*4+2)*4096 + node] + Zpart[(size_t)(modeA*4+3)*4096 + node];
  float zb = Zpart[(size_t)(modeB*4+0)*4096 + node] + Zpart[(size_t)(modeB*4+1)*4096 + node]
           + Zpart[(size_t)(modeB*4+2)*4096 + node] + Zpart[(size_t)(modeB*4+3)*4096 + node];
  float rza = 1.f / fmaxf(za, 1e-30f);
  float rzb = 1.f / fmaxf(zb, 1e-30f);
  float4 a0 = *(const float4*)(part + ((size_t)(modeA*2  )<<20) + l);
  float4 a1 = *(const float4*)(part + ((size_t)(modeA*2+1)<<20) + l);
  float4 b0 = *(const float4*)(part + ((size_t)(modeB*2  )<<20) + l);
  float4 b1 = *(const float4*)(part + ((size_t)(modeB*2+1)<<20) + l);
  float4 h4 = *(const float4*)(h + l);
  float4 o;
  o.x = lk(h4.x + (a0.x+a1.x)*rza + gam*(b0.x+b1.x)*rzb);
  o.y = lk(h4.y + (a0.y+a1.y)*rza + gam*(b0.y+b1.y)*rzb);
  o.z = lk(h4.z + (a0.z+a1.z)*rza + gam*(b0.z+b1.z)*rzb);
  o.w = lk(h4.w + (a0.w+a1.w)*rza + gam*(b0.w+b1.w)*rzb);
  *(float4*)(out + fid) = o;
}

// ---------------------------------------------------------------------------
extern "C" void kernel_launch(void* const* d_in, const int* in_sizes, int n_in,
                              void* d_out, int out_size, void* d_ws, size_t ws_size,
                              hipStream_t stream)
{
  const float* gene_x   = (const float*)d_in[0];
  const float* cell_x   = (const float*)d_in[1];
  const float* gene_adj = (const float*)d_in[2];
  const float* cell_adj = (const float*)d_in[3];
  const float* gc_adj   = (const float*)d_in[4];
  const float* Wg       = (const float*)d_in[5];
  const float* Wc       = (const float*)d_in[6];
  const float* a_gg     = (const float*)d_in[7];
  const float* a_gc     = (const float*)d_in[8];
  const float* a_cc     = (const float*)d_in[9];
  const float* a_cg     = (const float*)d_in[10];
  const float* gw_g     = (const float*)d_in[11];
  const float* gb_g     = (const float*)d_in[12];
  const float* gw_c     = (const float*)d_in[13];
  const float* gb_c     = (const float*)d_in[14];

  char* ws = (char*)d_ws;
  float* hg   = (float*)(ws);                    // 4MB
  float* hc   = (float*)(ws + (4u<<20));         // 4MB
  u16*   hTg  = (u16*)  (ws + (8u<<20));         // 2MB (tiled)
  u16*   hTc  = (u16*)  (ws + (10u<<20));        // 2MB (tiled)
  float* sbuf = (float*)(ws + (12u<<20));        // 160KB
  float* Zpart= (float*)(ws + (12u<<20) + (512u<<10)); // 256KB (16 x 4096 f32)
  uint8_t* bitsT = (uint8_t*)(ws + (13u<<20));   // 2MB
  u16*   Wgbf = (u16*)  (ws + (17u<<20));        // 0.5MB (overlaps part; used pre-k_gat)
  u16*   Wcbf = (u16*)  (ws + (17u<<20) + (512u<<10));
  float* part = (float*)(ws + (17u<<20));        // 32MB: [mode][kc][node][d]; ends 49MB
  u64*   packbits = (u64*)(ws + (49u<<20));      // 6MB: gene, cell, gc; ends 55MB

  k_wcvt<<<dim3(128), 256, 0, stream>>>(Wg, Wc, Wgbf, Wcbf);
  k_pack<<<dim3(3072), 256, 0, stream>>>(gene_adj, cell_adj, gc_adj, packbits);
  k_bitTT<<<dim3(1024), 256, 0, stream>>>(packbits + 524288, (u64*)bitsT);
  k_hgemm<<<dim3(64,2), 512, 0, stream>>>(gene_x, cell_x, Wgbf, Wcbf, hg, hc, hTg, hTc);
  k_svec<<<dim3(2048), 256, 0, stream>>>(hg, hc, a_gg, a_gc, a_cc, a_cg,
                                         gw_g, gb_g, gw_c, gb_c, sbuf);
  k_gat<<<dim3(64,2,4), 256, 0, stream>>>(sbuf, (const uint8_t*)packbits,
                                          bitsT, hTg, hTc, part, Zpart);
  k_epi<<<dim3(2048), 256, 0, stream>>>(hg, hc, part, Zpart, sbuf, (float*)d_out);
}

// Round 15
// 134.786 us; speedup vs baseline: 1.0667x; 1.0667x over previous
//
#include <hip/hip_runtime.h>
#include <stdint.h>

#define NGC 4096   // both node counts
#define FIN 512
#define DD  256

typedef __attribute__((ext_vector_type(8))) short short8;
typedef __attribute__((ext_vector_type(4))) float f32x4;
typedef unsigned short u16;
typedef unsigned int   u32;
typedef unsigned long long u64;

static __device__ __forceinline__ float bf2f(u16 u){ return __uint_as_float(((u32)u)<<16); }
static __device__ __forceinline__ u16 f2bf(float f){
  u32 u = __float_as_uint(f);
  u += 0x7fffu + ((u>>16)&1u);
  return (u16)(u>>16);
}
static __device__ __forceinline__ float lk(float x){ return fmaxf(x, 0.2f*x); }
static __device__ __forceinline__ u64 shfl_xor64(u64 x, int m){
  u32 lo = (u32)x, hi = (u32)(x >> 32);
  lo = __shfl_xor(lo, m); hi = __shfl_xor(hi, m);
  return ((u64)hi << 32) | lo;
}
// spread 16 bits so bit i lands at position 4*i
static __device__ __forceinline__ u64 spread4(u64 x){
  x &= 0xFFFFull;
  x = (x | (x << 24)) & 0x000000FF000000FFull;
  x = (x | (x << 12)) & 0x000F000F000F000Full;
  x = (x | (x << 6))  & 0x0303030303030303ull;
  x = (x | (x << 3))  & 0x1111111111111111ull;
  return x;
}
// async global->LDS: lds dest = uniform base + lane*16; global src per-lane.
static __device__ __forceinline__ void gl16(const void* g, void* l){
  __builtin_amdgcn_global_load_lds(
    (const __attribute__((address_space(1))) void*)g,
    (__attribute__((address_space(3))) void*)l, 16, 0, 0);
}

// ---------------------------------------------------------------------------
// k_wcvt: W (f32) -> bf16 copies for the GEMM.
// ---------------------------------------------------------------------------
__global__ __launch_bounds__(256) void k_wcvt(
    const float* __restrict__ Wg, const float* __restrict__ Wc,
    u16* __restrict__ Wgbf, u16* __restrict__ Wcbf)
{
  int base = (blockIdx.x*256 + threadIdx.x)*4;   // grid 128 -> 131072 elems
  float4 a = *(const float4*)(Wg + base);
  float4 b = *(const float4*)(Wc + base);
  ushort4 oa, ob;
  oa.x=f2bf(a.x); oa.y=f2bf(a.y); oa.z=f2bf(a.z); oa.w=f2bf(a.w);
  ob.x=f2bf(b.x); ob.y=f2bf(b.y); ob.z=f2bf(b.z); ob.w=f2bf(b.w);
  *(ushort4*)(Wgbf + base) = oa;
  *(ushort4*)(Wcbf + base) = ob;
}

// ---------------------------------------------------------------------------
// k_pack: bit-pack 3 adjacency matrices (f32 0/1 -> 1 bit), PLAIN layout:
// bit k of row r at u64 word [r*64 + k/64]. One wave per row.
// COALESCED loads (lane l reads elements j*256+l*4, wave instr = 1KB
// contiguous) + 4 ballots per j; lane keeps the ballots of j==lane>>2 and
// Morton-spreads its 16-bit slice -> word[lane] -> coalesced 512B store.
// (r14's per-lane-256B-span version was TA-bound: 64 sector reqs/instr.)
// ---------------------------------------------------------------------------
__global__ __launch_bounds__(256) void k_pack(
    const float* __restrict__ gene_adj, const float* __restrict__ cell_adj,
    const float* __restrict__ gc_adj,   u64* __restrict__ packbits)
{
  int t = threadIdx.x, wid = t>>6, lane = t&63;
  int gw = blockIdx.x*4 + wid;          // 0..12287
  int mat = gw >> 12;
  int row = gw & 4095;
  const float* src = (mat==0) ? gene_adj : (mat==1) ? cell_adj : gc_adj;
  const float* rp = src + (size_t)row*NGC + lane*4;

  float4 v[16];
  #pragma unroll
  for(int j = 0; j < 16; j++)
    v[j] = *(const float4*)(rp + j*256);

  const int sel = lane >> 2;
  u64 k0=0, k1=0, k2=0, k3=0;
  #pragma unroll
  for(int j = 0; j < 16; j++){
    u64 b0 = __ballot(v[j].x != 0.0f);
    u64 b1 = __ballot(v[j].y != 0.0f);
    u64 b2 = __ballot(v[j].z != 0.0f);
    u64 b3 = __ballot(v[j].w != 0.0f);
    if(sel == j){ k0=b0; k1=b1; k2=b2; k3=b3; }
  }
  int sh = (lane & 3) * 16;
  u64 w = spread4(k0 >> sh) | (spread4(k1 >> sh) << 1)
        | (spread4(k2 >> sh) << 2) | (spread4(k3 >> sh) << 3);
  packbits[((size_t)mat << 18) + (size_t)row*64 + lane] = w;
}

// ---------------------------------------------------------------------------
// k_bitTT: transpose gc bits -> bitsT (both PLAIN layout, u64 load/store).
// One wave per 64x64-bit tile; 4096 tiles; 4 waves/block -> 1024 blocks.
// ---------------------------------------------------------------------------
__global__ __launch_bounds__(256) void k_bitTT(
    const u64* __restrict__ gcb, u64* __restrict__ bT)
{
  int t = threadIdx.x, wid = t>>6, lane = t&63;
  int id = blockIdx.x*4 + wid;          // 0..4095
  int G = id & 63, C = id >> 6;

  u64 x = gcb[(size_t)(64*G + lane)*64 + C];

  const u64 M1  = 0xAAAAAAAAAAAAAAAAull;
  const u64 M2  = 0xCCCCCCCCCCCCCCCCull;
  const u64 M4  = 0xF0F0F0F0F0F0F0F0ull;
  const u64 M8  = 0xFF00FF00FF00FF00ull;
  const u64 M16 = 0xFFFF0000FFFF0000ull;
  const u64 M32 = 0xFFFFFFFF00000000ull;
  #define TSTEP(S, M) { u64 y = shfl_xor64(x, S); \
    x = (lane & S) ? ((x & (M)) | ((y >> S) & ~(M))) \
                   : ((x & ~(M)) | ((y << S) & (M))); }
  TSTEP(32, M32) TSTEP(16, M16) TSTEP(8, M8)
  TSTEP(4,  M4)  TSTEP(2,  M2)  TSTEP(1, M1)
  #undef TSTEP

  bT[(size_t)(64*C + lane)*64 + G] = x;
}

// ---------------------------------------------------------------------------
// k_hgemm: h = x @ W.T  (f32 x in -> bf16 staged, f32 h out + TILED bf16 hT)
// hTt layout: [kblock=k/32][dtile=d/16][kgrp=(k&31)/8][drow=d&15][k&7] so one
// MFMA A-fragment (16 d x 32 k = 1KB) is contiguous IN LANE-READ ORDER:
// lane (lrow,lhi) reads 16B at byte lhi*256+lrow*16 = lane*16.
// grid (64 row-tiles, 2 sides), 512 threads (8 waves). BM=64, BK=64, N=256.
// ---------------------------------------------------------------------------
__global__ __launch_bounds__(512) void k_hgemm(
    const float* __restrict__ xg, const float* __restrict__ xc,
    const u16* __restrict__ Wg, const u16* __restrict__ Wc,
    float* __restrict__ hg, float* __restrict__ hc,
    u16* __restrict__ hTg, u16* __restrict__ hTc)
{
  const int side = blockIdx.y;
  const float* x = side ? xc : xg;
  const u16* W = side ? Wc : Wg;
  float* h  = side ? hc : hg;
  u16*  hT  = side ? hTc : hTg;
  const int r0 = blockIdx.x * 64;
  const int t = threadIdx.x;
  const int wid = t >> 6, lane = t & 63;
  const int lrow = lane & 15, lhi = lane >> 4;

  __shared__ __align__(16) char smem[32768];

  f32x4 acc[4][2];
  const f32x4 z4 = {0.f,0.f,0.f,0.f};
  #pragma unroll
  for(int i=0;i<4;i++){ acc[i][0]=z4; acc[i][1]=z4; }

  const int r = t >> 3, c8 = t & 7;
  for(int k0 = 0; k0 < FIN; k0 += 64){
    const float* xp = x + (size_t)(r0 + r)*FIN + k0 + c8*8;
    float4 xa = *(const float4*)xp;
    float4 xb = *(const float4*)(xp + 4);
    short8 xv;
    xv[0]=(short)f2bf(xa.x); xv[1]=(short)f2bf(xa.y);
    xv[2]=(short)f2bf(xa.z); xv[3]=(short)f2bf(xa.w);
    xv[4]=(short)f2bf(xb.x); xv[5]=(short)f2bf(xb.y);
    xv[6]=(short)f2bf(xb.z); xv[7]=(short)f2bf(xb.w);
    int wbyte = r*128 + (((c8 ^ (r & 7)) & 7) << 4);
    *(short8*)(smem + wbyte) = xv;
    __syncthreads();
    #pragma unroll
    for(int ksub = 0; ksub < 2; ksub++){
      short8 b[2];
      #pragma unroll
      for(int nf=0; nf<2; nf++){
        int n = wid*32 + nf*16 + lrow;
        b[nf] = *(const short8*)(W + (size_t)n*FIN + k0 + ksub*32 + lhi*8);
      }
      #pragma unroll
      for(int mf=0; mf<4; mf++){
        int row = mf*16 + lrow;
        int g = ksub*4 + lhi;
        short8 a = *(const short8*)(smem + row*128 + (((g ^ (row & 7)) & 7) << 4));
        #pragma unroll
        for(int nf=0; nf<2; nf++)
          acc[mf][nf] = __builtin_amdgcn_mfma_f32_16x16x32_bf16(a, b[nf], acc[mf][nf], 0,0,0);
      }
    }
    __syncthreads();
  }
  // write h (f32) and stage bf16 transpose in LDS
  #pragma unroll
  for(int mf=0; mf<4; mf++){
    #pragma unroll
    for(int nf=0; nf<2; nf++){
      int col = wid*32 + nf*16 + lrow;
      #pragma unroll
      for(int j=0;j<4;j++){
        int row = mf*16 + lhi*4 + j;
        float v = acc[mf][nf][j];
        h[(size_t)(r0+row)*DD + col] = v;
        int byte_ = col*128 + (((row*2) ^ ((col & 7)<<4)));
        *(u16*)(smem + byte_) = f2bf(v);
      }
    }
  }
  __syncthreads();
  { // tiled hT store (read-order layout): thread -> (n = t>>1 d-row, half)
    int n = t >> 1, half = t & 1;
    #pragma unroll
    for(int gi=0; gi<4; gi++){
      int g = half*4 + gi;
      int byte_ = n*128 + (((g ^ (n & 7)) & 7) << 4);
      short8 v = *(const short8*)(smem + byte_);
      int kcol = r0 + g*8;   // global k (node) index, 8-aligned
      size_t off = (size_t)(kcol>>5)*8192 + (size_t)(n>>4)*512
                 + ((kcol>>3)&3)*128 + (n&15)*8;
      *(short8*)(hT + off) = v;
    }
  }
}

// ---------------------------------------------------------------------------
// k_svec: per-row dot products with attention vectors + gate sigmoid.
// sbuf layout (each 4096 f32):
// 0 s1gg 1 s2gg 2 s1gc 3 s2cg 4 gam_g 5 s1cc 6 s2cc 7 s2gc 8 s1cg 9 gam_c
// ---------------------------------------------------------------------------
__global__ __launch_bounds__(256) void k_svec(
    const float* __restrict__ hg, const float* __restrict__ hc,
    const float* __restrict__ a_gg, const float* __restrict__ a_gc,
    const float* __restrict__ a_cc, const float* __restrict__ a_cg,
    const float* __restrict__ gw_g, const float* __restrict__ gb_g,
    const float* __restrict__ gw_c, const float* __restrict__ gb_c,
    float* __restrict__ sbuf)
{
  int t = threadIdx.x, wid = t>>6, lane = t&63;
  int idx = blockIdx.x * 4 + wid;          // 0..8191
  int side = idx >> 12;
  int row  = idx & 4095;
  const float* h = (side ? hc : hg) + (size_t)row*DD;
  const float* v0 = (side ? a_cc : a_gg);        // same-type s1 half
  const float* v1 = (side ? a_cc : a_gg) + DD;   // same-type s2 half
  const float* v2 = (side ? a_cg : a_gc);        // cross s1 (this node as src)
  const float* v3 = (side ? a_gc : a_cg) + DD;   // cross s2 (this node as dst)
  const float* gw = side ? gw_c : gw_g;
  float bias = (side ? gb_c : gb_g)[0];

  float4 hv = *(const float4*)(h + lane*4);
  float4 w0 = *(const float4*)(v0 + lane*4);
  float4 w1 = *(const float4*)(v1 + lane*4);
  float4 w2 = *(const float4*)(v2 + lane*4);
  float4 w3 = *(const float4*)(v3 + lane*4);
  float4 w4 = *(const float4*)(gw + lane*4);

  float d0 = hv.x*w0.x + hv.y*w0.y + hv.z*w0.z + hv.w*w0.w;
  float d1 = hv.x*w1.x + hv.y*w1.y + hv.z*w1.z + hv.w*w1.w;
  float d2 = hv.x*w2.x + hv.y*w2.y + hv.z*w2.z + hv.w*w2.w;
  float d3 = hv.x*w3.x + hv.y*w3.y + hv.z*w3.z + hv.w*w3.w;
  float d4 = hv.x*w4.x + hv.y*w4.y + hv.z*w4.z + hv.w*w4.w;
  #pragma unroll
  for(int s=1;s<64;s<<=1){
    d0 += __shfl_xor(d0, s); d1 += __shfl_xor(d1, s); d2 += __shfl_xor(d2, s);
    d3 += __shfl_xor(d3, s); d4 += __shfl_xor(d4, s);
  }
  if(lane == 0){
    float gam = 1.f/(1.f + __expf(-(d4 + bias)));
    if(side == 0){
      sbuf[0*4096+row]=d0; sbuf[1*4096+row]=d1; sbuf[2*4096+row]=d2;
      sbuf[3*4096+row]=d3; sbuf[4*4096+row]=gam;
    } else {
      sbuf[5*4096+row]=d0; sbuf[6*4096+row]=d1; sbuf[8*4096+row]=d2;
      sbuf[7*4096+row]=d3; sbuf[9*4096+row]=gam;
    }
  }
}

// ---------------------------------------------------------------------------
// k_gat: O^T = V^T * P^T, P generated in-register as the MFMA B-operand.
// grid (64 ng, 2 kc, 4 modes) x 256 thr (4 waves: 2 kh x 2 ng).
// A staged in LDS (global_load_lds, double-buffered, 32KB/step) and SHARED
// by the ng waves; conflict-free ds_read_b128 (fragment in lane-read order).
// One barrier/step; staging issued at step top so exp+MFMA hides L2 latency.
// Masks in XOR-swizzled LDS; s2 register-prefetched. 80KB LDS -> 2 blocks/CU.
// ---------------------------------------------------------------------------
__global__ __launch_bounds__(256,2) void k_gat(
    const float* __restrict__ sbuf,
    const uint8_t* __restrict__ packbits, const uint8_t* __restrict__ bitsT,
    const u16* __restrict__ hTg, const u16* __restrict__ hTc,
    float* __restrict__ part, float* __restrict__ Zpart)
{
  const int mode = blockIdx.z;
  const int kc   = blockIdx.y;
  const int nodebase = blockIdx.x * 64;
  const int kcbase   = kc * 2048;

  const float* s1; const float* s2; const uint8_t* bits; const u16* hT;
  if(mode == 0){ s1 = sbuf;        s2 = sbuf+4096;   bits = packbits;           hT = hTg; }
  else if(mode == 1){ s1 = sbuf+2*4096; s2 = sbuf+7*4096; bits = packbits+4194304; hT = hTc; }
  else if(mode == 2){ s1 = sbuf+5*4096; s2 = sbuf+6*4096; bits = packbits+2097152; hT = hTc; }
  else { s1 = sbuf+8*4096; s2 = sbuf+3*4096; bits = bitsT; hT = hTg; }

  const int t = threadIdx.x, wid = t>>6, lane = t&63, lrow = lane&15, lhi = lane>>4;
  const int kh = wid >> 1;        // k-half of the 2048 chunk
  const int ng_sub = wid & 1;     // 32-node group

  __shared__ __align__(16) char U[81920];
  char* A_lds  = U;               // [2 dbuf][2 kh][16KB]
  char* mask_l = U + 65536;       // [64 rows][256B], 16B-slot XOR-swizzled

  // ---- prologue: stage masks (16KB, swizzled 16B slots) ----
  {
    int row = t>>2, seg = t&3;
    const char* g = (const char*)bits + (size_t)(nodebase+row)*512 + kc*256 + seg*64;
    char* drow_ = mask_l + row*256;
    #pragma unroll
    for(int i=0;i<4;i++){
      int slot = seg*4 + i;
      *(ulonglong2*)(drow_ + (((slot ^ (row&7)))<<4)) = *(const ulonglong2*)(g + i*16);
    }
  }
  // ---- prologue: stage A step 0 into buf0 (each wave: its kh, its half) ----
  const char* hTb = (const char*)hT;
  {
    const char* g = hTb + ((size_t)kc*64 + kh*32 + 0)*16384 + ng_sub*8192 + lane*16;
    char* l = A_lds + 0*32768 + kh*16384 + ng_sub*8192;
    #pragma unroll
    for(int i=0;i<8;i++) gl16(g + i*1024, l + i*1024);
  }
  // ---- per-wave global max over FULL s2 (no cross-wave reduce needed) ----
  float mxv = -1e30f;
  #pragma unroll
  for(int i=0;i<16;i++){
    float4 v = *(const float4*)(s2 + lane*64 + i*4);
    mxv = fmaxf(mxv, fmaxf(fmaxf(v.x,v.y), fmaxf(v.z,v.w)));
  }
  #pragma unroll
  for(int sh=1; sh<64; sh<<=1) mxv = fmaxf(mxv, __shfl_xor(mxv, sh));
  const float maxs2 = mxv;

  const int wnode = nodebase + ng_sub*32;
  const float L2E = 1.4426950408889634f;
  float c1[2], c2[2], z[2];
  #pragma unroll
  for(int nf=0; nf<2; nf++){
    float s1v = s1[wnode + nf*16 + lrow];
    float m = lk(s1v + maxs2);
    c1[nf] = (s1v - m)*L2E;
    c2[nf] = (0.2f*s1v - m)*L2E;
    z[nf] = 0.f;
  }

  f32x4 acc[16][2];
  const f32x4 zz = {0.f,0.f,0.f,0.f};
  #pragma unroll
  for(int i=0;i<16;i++){ acc[i][0]=zz; acc[i][1]=zz; }

  const float* s2g = s2 + kcbase + kh*1024 + lhi*8;
  const char* mrow0 = mask_l + (ng_sub*32 + lrow)*256;
  const char* mrow1 = mask_l + (ng_sub*32 + 16 + lrow)*256;
  const int mx0 = (ng_sub*32 + lrow) & 7, mx1 = (ng_sub*32 + 16 + lrow) & 7;

  // s2 register prefetch for step 0
  float4 csA = *(const float4*)(s2g);
  float4 csB = *(const float4*)(s2g + 4);

  __syncthreads();   // masks + A step0 staged (vmcnt drained)

  // ---- main loop: 32 steps, 1 barrier/step ----
  #pragma unroll 1
  for(int s=0; s<32; s++){
    const int cur = s & 1;
    // stage step s+1 into buf^1 (hidden under this step's compute)
    if(s < 31){
      const char* g = hTb + ((size_t)kc*64 + kh*32 + s + 1)*16384 + ng_sub*8192 + lane*16;
      char* l = A_lds + (cur^1)*32768 + kh*16384 + ng_sub*8192;
      #pragma unroll
      for(int i=0;i<8;i++) gl16(g + i*1024, l + i*1024);
    }
    float4 sA = csA, sB = csB;
    if(s < 31){
      csA = *(const float4*)(s2g + (s+1)*32);
      csB = *(const float4*)(s2g + (s+1)*32 + 4);
    }
    float e1[8], e2[8];
    {
      float sv[8] = {sA.x,sA.y,sA.z,sA.w,sB.x,sB.y,sB.z,sB.w};
      #pragma unroll
      for(int j=0;j<8;j++){ e1[j] = sv[j]*L2E; e2[j] = sv[j]*(0.2f*L2E); }
    }
    // mask words (swizzled slot): wb = kh*128 + s*4
    const int slot = kh*8 + (s>>2), win = (s&3)*4;
    u32 mw0 = *(const u32*)(mrow0 + ((slot ^ mx0)<<4) + win);
    u32 mw1 = *(const u32*)(mrow1 + ((slot ^ mx1)<<4) + win);
    short8 b[2];
    #pragma unroll
    for(int nf=0; nf<2; nf++){
      u32 mw = nf ? mw1 : mw0;
      u32 w4[4];
      #pragma unroll
      for(int pr=0; pr<4; pr++){
        float bit0 = (float)((mw >> (lhi*8 + 2*pr  )) & 1u);
        float bit1 = (float)((mw >> (lhi*8 + 2*pr+1)) & 1u);
        float p0 = __builtin_amdgcn_exp2f(fmaxf(c1[nf]+e1[2*pr  ], c2[nf]+e2[2*pr  ])) * bit0;
        float p1 = __builtin_amdgcn_exp2f(fmaxf(c1[nf]+e1[2*pr+1], c2[nf]+e2[2*pr+1])) * bit1;
        z[nf] += p0 + p1;
        u32 q0 = __float_as_uint(p0) + 0x8000u;
        u32 q1 = __float_as_uint(p1) + 0x8000u;
        w4[pr] = (q1 & 0xFFFF0000u) | (q0 >> 16);
      }
      union{ u32 u[4]; short8 s8; } cv;
      cv.u[0]=w4[0]; cv.u[1]=w4[1]; cv.u[2]=w4[2]; cv.u[3]=w4[3];
      b[nf] = cv.s8;
    }
    // A from LDS (conflict-free: lane reads byte lane*16 of each 1KB frag)
    const char* Af = A_lds + cur*32768 + kh*16384 + lane*16;
    #pragma unroll
    for(int mf=0; mf<16; mf++){
      short8 a = *(const short8*)(Af + mf*1024);
      acc[mf][0] = __builtin_amdgcn_mfma_f32_16x16x32_bf16(a, b[0], acc[mf][0], 0,0,0);
      acc[mf][1] = __builtin_amdgcn_mfma_f32_16x16x32_bf16(a, b[1], acc[mf][1], 0,0,0);
    }
    __syncthreads();   // protects buf reuse + completes s+1 staging
  }

  // ---- Z: reduce across lhi, write per-(kc,kh) slot; k_epi sums 4 ----
  #pragma unroll
  for(int nf=0; nf<2; nf++){
    z[nf] += __shfl_xor(z[nf], 16);
    z[nf] += __shfl_xor(z[nf], 32);
  }
  if(lhi == 0){
    float* zp = Zpart + (size_t)(mode*4 + kc*2 + kh)*4096 + wnode;
    zp[lrow]      = z[0];
    zp[16 + lrow] = z[1];
  }

  // ---- kh-reduce via 32KB swizzled LDS (two 8-mf rounds), then store ----
  __syncthreads();                 // loop done; A_lds free
  float* R = (float*)A_lds;        // [64 rows][128 f32], XOR-swizzled
  float* po = part + ((size_t)(mode*2 + kc) << 20);
  #pragma unroll
  for(int half=0; half<2; half++){
    if(kh == 1){
      #pragma unroll
      for(int mf8=0; mf8<8; mf8++){
        #pragma unroll
        for(int nf=0; nf<2; nf++){
          int r = ng_sub*32 + nf*16 + lrow;
          int byte_ = r*512 + ((mf8*64 + lhi*16) ^ ((r&7)<<4));
          *(f32x4*)((char*)R + byte_) = acc[half*8 + mf8][nf];
        }
      }
    }
    __syncthreads();
    if(kh == 0){
      #pragma unroll
      for(int mf8=0; mf8<8; mf8++){
        #pragma unroll
        for(int nf=0; nf<2; nf++){
          int r = ng_sub*32 + nf*16 + lrow;
          int byte_ = r*512 + ((mf8*64 + lhi*16) ^ ((r&7)<<4));
          f32x4 o = *(const f32x4*)((const char*)R + byte_);
          o = o + acc[half*8 + mf8][nf];
          int node = nodebase + r;
          *(f32x4*)(po + (size_t)node*256 + (half*8+mf8)*16 + lhi*4) = o;
        }
      }
    }
    __syncthreads();
  }
}

// ---------------------------------------------------------------------------
// k_epi: out = leaky(h + sum(A)/za + gamma*sum(B)/zb), fused kc/kh-reduce.
// ---------------------------------------------------------------------------
__global__ __launch_bounds__(256) void k_epi(
    const float* __restrict__ hg, const float* __restrict__ hc,
    const float* __restrict__ part, const float* __restrict__ Zpart,
    const float* __restrict__ sbuf, float* __restrict__ out)
{
  int idx = blockIdx.x*256 + threadIdx.x;   // 0..524287
  int fid = idx*4;
  int side = fid >> 20;
  int l = fid & 1048575;
  int node = l >> 8;
  int modeA = side ? 2 : 0, modeB = side ? 3 : 1;
  const float* h = side ? hc : hg;
  float gam = sbuf[(side ? 9 : 4)*4096 + node];
  float za = Zpart[(size_t)(modeA*4+0)*4096 + node] + Zpart[(size_t)(modeA*4+1)*4096 + node]
           + Zpart[(size_t)(modeA*4+2)*4096 + node] + Zpart[(size_t)(modeA*4+3)*4096 + node];
  float zb = Zpart[(size_t)(modeB*4+0)*4096 + node] + Zpart[(size_t)(modeB*4+1)*4096 + node]
           + Zpart[(size_t)(modeB*4+2)*4096 + node] + Zpart[(size_t)(modeB*4+3)*4096 + node];
  float rza = 1.f / fmaxf(za, 1e-30f);
  float rzb = 1.f / fmaxf(zb, 1e-30f);
  float4 a0 = *(const float4*)(part + ((size_t)(modeA*2  )<<20) + l);
  float4 a1 = *(const float4*)(part + ((size_t)(modeA*2+1)<<20) + l);
  float4 b0 = *(const float4*)(part + ((size_t)(modeB*2  )<<20) + l);
  float4 b1 = *(const float4*)(part + ((size_t)(modeB*2+1)<<20) + l);
  float4 h4 = *(const float4*)(h + l);
  float4 o;
  o.x = lk(h4.x + (a0.x+a1.x)*rza + gam*(b0.x+b1.x)*rzb);
  o.y = lk(h4.y + (a0.y+a1.y)*rza + gam*(b0.y+b1.y)*rzb);
  o.z = lk(h4.z + (a0.z+a1.z)*rza + gam*(b0.z+b1.z)*rzb);
  o.w = lk(h4.w + (a0.w+a1.w)*rza + gam*(b0.w+b1.w)*rzb);
  *(float4*)(out + fid) = o;
}

// ---------------------------------------------------------------------------
extern "C" void kernel_launch(void* const* d_in, const int* in_sizes, int n_in,
                              void* d_out, int out_size, void* d_ws, size_t ws_size,
                              hipStream_t stream)
{
  const float* gene_x   = (const float*)d_in[0];
  const float* cell_x   = (const float*)d_in[1];
  const float* gene_adj = (const float*)d_in[2];
  const float* cell_adj = (const float*)d_in[3];
  const float* gc_adj   = (const float*)d_in[4];
  const float* Wg       = (const float*)d_in[5];
  const float* Wc       = (const float*)d_in[6];
  const float* a_gg     = (const float*)d_in[7];
  const float* a_gc     = (const float*)d_in[8];
  const float* a_cc     = (const float*)d_in[9];
  const float* a_cg     = (const float*)d_in[10];
  const float* gw_g     = (const float*)d_in[11];
  const float* gb_g     = (const float*)d_in[12];
  const float* gw_c     = (const float*)d_in[13];
  const float* gb_c     = (const float*)d_in[14];

  char* ws = (char*)d_ws;
  float* hg   = (float*)(ws);                    // 4MB
  float* hc   = (float*)(ws + (4u<<20));         // 4MB
  u16*   hTg  = (u16*)  (ws + (8u<<20));         // 2MB (tiled)
  u16*   hTc  = (u16*)  (ws + (10u<<20));        // 2MB (tiled)
  float* sbuf = (float*)(ws + (12u<<20));        // 160KB
  float* Zpart= (float*)(ws + (12u<<20) + (512u<<10)); // 256KB (16 x 4096 f32)
  uint8_t* bitsT = (uint8_t*)(ws + (13u<<20));   // 2MB
  u16*   Wgbf = (u16*)  (ws + (17u<<20));        // 0.5MB (overlaps part; used pre-k_gat)
  u16*   Wcbf = (u16*)  (ws + (17u<<20) + (512u<<10));
  float* part = (float*)(ws + (17u<<20));        // 32MB: [mode][kc][node][d]; ends 49MB
  u64*   packbits = (u64*)(ws + (49u<<20));      // 6MB: gene, cell, gc; ends 55MB

  k_wcvt<<<dim3(128), 256, 0, stream>>>(Wg, Wc, Wgbf, Wcbf);
  k_pack<<<dim3(3072), 256, 0, stream>>>(gene_adj, cell_adj, gc_adj, packbits);
  k_bitTT<<<dim3(1024), 256, 0, stream>>>(packbits + 524288, (u64*)bitsT);
  k_hgemm<<<dim3(64,2), 512, 0, stream>>>(gene_x, cell_x, Wgbf, Wcbf, hg, hc, hTg, hTc);
  k_svec<<<dim3(2048), 256, 0, stream>>>(hg, hc, a_gg, a_gc, a_cc, a_cg,
                                         gw_g, gb_g, gw_c, gb_c, sbuf);
  k_gat<<<dim3(64,2,4), 256, 0, stream>>>(sbuf, (const uint8_t*)packbits,
                                          bitsT, hTg, hTc, part, Zpart);
  k_epi<<<dim3(2048), 256, 0, stream>>>(hg, hc, part, Zpart, sbuf, (float*)d_out);
}

// Round 16
// 134.443 us; speedup vs baseline: 1.0694x; 1.0026x over previous
//
#include <hip/hip_runtime.h>
#include <stdint.h>

#define NGC 4096   // both node counts
#define FIN 512
#define DD  256

typedef __attribute__((ext_vector_type(8))) short short8;
typedef __attribute__((ext_vector_type(4))) float f32x4;
typedef unsigned short u16;
typedef unsigned int   u32;
typedef unsigned long long u64;

static __device__ __forceinline__ float bf2f(u16 u){ return __uint_as_float(((u32)u)<<16); }
static __device__ __forceinline__ u16 f2bf(float f){
  u32 u = __float_as_uint(f);
  u += 0x7fffu + ((u>>16)&1u);
  return (u16)(u>>16);
}
static __device__ __forceinline__ float lk(float x){ return fmaxf(x, 0.2f*x); }
static __device__ __forceinline__ u64 shfl_xor64(u64 x, int m){
  u32 lo = (u32)x, hi = (u32)(x >> 32);
  lo = __shfl_xor(lo, m); hi = __shfl_xor(hi, m);
  return ((u64)hi << 32) | lo;
}
// spread 16 bits so bit i lands at position 4*i
static __device__ __forceinline__ u64 spread4(u64 x){
  x &= 0xFFFFull;
  x = (x | (x << 24)) & 0x000000FF000000FFull;
  x = (x | (x << 12)) & 0x000F000F000F000Full;
  x = (x | (x << 6))  & 0x0303030303030303ull;
  x = (x | (x << 3))  & 0x1111111111111111ull;
  return x;
}
// async global->LDS: lds dest = uniform base + lane*16; global src per-lane.
static __device__ __forceinline__ void gl16(const void* g, void* l){
  __builtin_amdgcn_global_load_lds(
    (const __attribute__((address_space(1))) void*)g,
    (__attribute__((address_space(3))) void*)l, 16, 0, 0);
}

// ---------------------------------------------------------------------------
// k_wcvt: W (f32) -> bf16 copies for the GEMM.
// ---------------------------------------------------------------------------
__global__ __launch_bounds__(256) void k_wcvt(
    const float* __restrict__ Wg, const float* __restrict__ Wc,
    u16* __restrict__ Wgbf, u16* __restrict__ Wcbf)
{
  int base = (blockIdx.x*256 + threadIdx.x)*4;   // grid 128 -> 131072 elems
  float4 a = *(const float4*)(Wg + base);
  float4 b = *(const float4*)(Wc + base);
  ushort4 oa, ob;
  oa.x=f2bf(a.x); oa.y=f2bf(a.y); oa.z=f2bf(a.z); oa.w=f2bf(a.w);
  ob.x=f2bf(b.x); ob.y=f2bf(b.y); ob.z=f2bf(b.z); ob.w=f2bf(b.w);
  *(ushort4*)(Wgbf + base) = oa;
  *(ushort4*)(Wcbf + base) = ob;
}

// ---------------------------------------------------------------------------
// k_pack: bit-pack 3 adjacency matrices (f32 0/1 -> 1 bit), PLAIN layout:
// bit k of row r at u64 word [r*64 + k/64]. PERSISTENT waves: 2048 waves x
// 6 rows each, register double-buffered (row i+1's 16 coalesced float4
// loads issued before row i's ballots) so the HBM stream never drains.
// (r13-r15 single-row-per-wave variants all plateaued at ~71us: load burst
// + wave teardown duty cycle capped effective BW at 2.7 TB/s.)
// ---------------------------------------------------------------------------
__global__ __launch_bounds__(256) void k_pack(
    const float* __restrict__ gene_adj, const float* __restrict__ cell_adj,
    const float* __restrict__ gc_adj,   u64* __restrict__ packbits)
{
  int t = threadIdx.x, wid = t>>6, lane = t&63;
  int w = blockIdx.x*4 + wid;           // 0..2047
  int row0 = w*6;
  const int sel = lane >> 2;
  const int sh = (lane & 3) * 16;

  float4 bufA[16], bufB[16];

  // prologue: load row0 into bufA
  {
    int m = row0 >> 12;
    const float* sp = (m==0) ? gene_adj : (m==1) ? cell_adj : gc_adj;
    const float* rp = sp + (size_t)(row0 & 4095)*NGC + lane*4;
    #pragma unroll
    for(int j=0;j<16;j++) bufA[j] = *(const float4*)(rp + j*256);
  }

  #pragma unroll
  for(int i=0;i<6;i++){
    const bool evn = (i & 1) == 0;
    // issue next row's loads into the other buffer
    if(i < 5){
      int row = row0 + i + 1;
      int m = row >> 12;
      const float* sp = (m==0) ? gene_adj : (m==1) ? cell_adj : gc_adj;
      const float* rp = sp + (size_t)(row & 4095)*NGC + lane*4;
      if(evn){
        #pragma unroll
        for(int j=0;j<16;j++) bufB[j] = *(const float4*)(rp + j*256);
      } else {
        #pragma unroll
        for(int j=0;j<16;j++) bufA[j] = *(const float4*)(rp + j*256);
      }
    }
    // ballots on current buffer
    u64 k0=0, k1=0, k2=0, k3=0;
    #pragma unroll
    for(int j=0;j<16;j++){
      float4 v = evn ? bufA[j] : bufB[j];
      u64 b0 = __ballot(v.x != 0.0f);
      u64 b1 = __ballot(v.y != 0.0f);
      u64 b2 = __ballot(v.z != 0.0f);
      u64 b3 = __ballot(v.w != 0.0f);
      if(sel == j){ k0=b0; k1=b1; k2=b2; k3=b3; }
    }
    u64 wv = spread4(k0 >> sh) | (spread4(k1 >> sh) << 1)
           | (spread4(k2 >> sh) << 2) | (spread4(k3 >> sh) << 3);
    int row = row0 + i;
    packbits[((size_t)(row >> 12) << 18) + (size_t)(row & 4095)*64 + lane] = wv;
  }
}

// ---------------------------------------------------------------------------
// k_bitTT: transpose gc bits -> bitsT (both PLAIN layout, u64 load/store).
// One wave per 64x64-bit tile; 4096 tiles; 4 waves/block -> 1024 blocks.
// ---------------------------------------------------------------------------
__global__ __launch_bounds__(256) void k_bitTT(
    const u64* __restrict__ gcb, u64* __restrict__ bT)
{
  int t = threadIdx.x, wid = t>>6, lane = t&63;
  int id = blockIdx.x*4 + wid;          // 0..4095
  int G = id & 63, C = id >> 6;

  u64 x = gcb[(size_t)(64*G + lane)*64 + C];

  const u64 M1  = 0xAAAAAAAAAAAAAAAAull;
  const u64 M2  = 0xCCCCCCCCCCCCCCCCull;
  const u64 M4  = 0xF0F0F0F0F0F0F0F0ull;
  const u64 M8  = 0xFF00FF00FF00FF00ull;
  const u64 M16 = 0xFFFF0000FFFF0000ull;
  const u64 M32 = 0xFFFFFFFF00000000ull;
  #define TSTEP(S, M) { u64 y = shfl_xor64(x, S); \
    x = (lane & S) ? ((x & (M)) | ((y >> S) & ~(M))) \
                   : ((x & ~(M)) | ((y << S) & (M))); }
  TSTEP(32, M32) TSTEP(16, M16) TSTEP(8, M8)
  TSTEP(4,  M4)  TSTEP(2,  M2)  TSTEP(1, M1)
  #undef TSTEP

  bT[(size_t)(64*C + lane)*64 + G] = x;
}

// ---------------------------------------------------------------------------
// k_hgemm: h = x @ W.T  (f32 x in -> bf16 staged, f32 h out + TILED bf16 hT)
// hTt layout: [kblock=k/32][dtile=d/16][kgrp=(k&31)/8][drow=d&15][k&7] so one
// MFMA A-fragment (16 d x 32 k = 1KB) is contiguous IN LANE-READ ORDER:
// lane (lrow,lhi) reads 16B at byte lhi*256+lrow*16 = lane*16.
// grid (64 row-tiles, 2 sides), 512 threads (8 waves). BM=64, BK=64, N=256.
// ---------------------------------------------------------------------------
__global__ __launch_bounds__(512) void k_hgemm(
    const float* __restrict__ xg, const float* __restrict__ xc,
    const u16* __restrict__ Wg, const u16* __restrict__ Wc,
    float* __restrict__ hg, float* __restrict__ hc,
    u16* __restrict__ hTg, u16* __restrict__ hTc)
{
  const int side = blockIdx.y;
  const float* x = side ? xc : xg;
  const u16* W = side ? Wc : Wg;
  float* h  = side ? hc : hg;
  u16*  hT  = side ? hTc : hTg;
  const int r0 = blockIdx.x * 64;
  const int t = threadIdx.x;
  const int wid = t >> 6, lane = t & 63;
  const int lrow = lane & 15, lhi = lane >> 4;

  __shared__ __align__(16) char smem[32768];

  f32x4 acc[4][2];
  const f32x4 z4 = {0.f,0.f,0.f,0.f};
  #pragma unroll
  for(int i=0;i<4;i++){ acc[i][0]=z4; acc[i][1]=z4; }

  const int r = t >> 3, c8 = t & 7;
  for(int k0 = 0; k0 < FIN; k0 += 64){
    const float* xp = x + (size_t)(r0 + r)*FIN + k0 + c8*8;
    float4 xa = *(const float4*)xp;
    float4 xb = *(const float4*)(xp + 4);
    short8 xv;
    xv[0]=(short)f2bf(xa.x); xv[1]=(short)f2bf(xa.y);
    xv[2]=(short)f2bf(xa.z); xv[3]=(short)f2bf(xa.w);
    xv[4]=(short)f2bf(xb.x); xv[5]=(short)f2bf(xb.y);
    xv[6]=(short)f2bf(xb.z); xv[7]=(short)f2bf(xb.w);
    int wbyte = r*128 + (((c8 ^ (r & 7)) & 7) << 4);
    *(short8*)(smem + wbyte) = xv;
    __syncthreads();
    #pragma unroll
    for(int ksub = 0; ksub < 2; ksub++){
      short8 b[2];
      #pragma unroll
      for(int nf=0; nf<2; nf++){
        int n = wid*32 + nf*16 + lrow;
        b[nf] = *(const short8*)(W + (size_t)n*FIN + k0 + ksub*32 + lhi*8);
      }
      #pragma unroll
      for(int mf=0; mf<4; mf++){
        int row = mf*16 + lrow;
        int g = ksub*4 + lhi;
        short8 a = *(const short8*)(smem + row*128 + (((g ^ (row & 7)) & 7) << 4));
        #pragma unroll
        for(int nf=0; nf<2; nf++)
          acc[mf][nf] = __builtin_amdgcn_mfma_f32_16x16x32_bf16(a, b[nf], acc[mf][nf], 0,0,0);
      }
    }
    __syncthreads();
  }
  // write h (f32) and stage bf16 transpose in LDS
  #pragma unroll
  for(int mf=0; mf<4; mf++){
    #pragma unroll
    for(int nf=0; nf<2; nf++){
      int col = wid*32 + nf*16 + lrow;
      #pragma unroll
      for(int j=0;j<4;j++){
        int row = mf*16 + lhi*4 + j;
        float v = acc[mf][nf][j];
        h[(size_t)(r0+row)*DD + col] = v;
        int byte_ = col*128 + (((row*2) ^ ((col & 7)<<4)));
        *(u16*)(smem + byte_) = f2bf(v);
      }
    }
  }
  __syncthreads();
  { // tiled hT store (read-order layout): thread -> (n = t>>1 d-row, half)
    int n = t >> 1, half = t & 1;
    #pragma unroll
    for(int gi=0; gi<4; gi++){
      int g = half*4 + gi;
      int byte_ = n*128 + (((g ^ (n & 7)) & 7) << 4);
      short8 v = *(const short8*)(smem + byte_);
      int kcol = r0 + g*8;   // global k (node) index, 8-aligned
      size_t off = (size_t)(kcol>>5)*8192 + (size_t)(n>>4)*512
                 + ((kcol>>3)&3)*128 + (n&15)*8;
      *(short8*)(hT + off) = v;
    }
  }
}

// ---------------------------------------------------------------------------
// k_svec: per-row dot products with attention vectors + gate sigmoid.
// sbuf layout (each 4096 f32):
// 0 s1gg 1 s2gg 2 s1gc 3 s2cg 4 gam_g 5 s1cc 6 s2cc 7 s2gc 8 s1cg 9 gam_c
// ---------------------------------------------------------------------------
__global__ __launch_bounds__(256) void k_svec(
    const float* __restrict__ hg, const float* __restrict__ hc,
    const float* __restrict__ a_gg, const float* __restrict__ a_gc,
    const float* __restrict__ a_cc, const float* __restrict__ a_cg,
    const float* __restrict__ gw_g, const float* __restrict__ gb_g,
    const float* __restrict__ gw_c, const float* __restrict__ gb_c,
    float* __restrict__ sbuf)
{
  int t = threadIdx.x, wid = t>>6, lane = t&63;
  int idx = blockIdx.x * 4 + wid;          // 0..8191
  int side = idx >> 12;
  int row  = idx & 4095;
  const float* h = (side ? hc : hg) + (size_t)row*DD;
  const float* v0 = (side ? a_cc : a_gg);        // same-type s1 half
  const float* v1 = (side ? a_cc : a_gg) + DD;   // same-type s2 half
  const float* v2 = (side ? a_cg : a_gc);        // cross s1 (this node as src)
  const float* v3 = (side ? a_gc : a_cg) + DD;   // cross s2 (this node as dst)
  const float* gw = side ? gw_c : gw_g;
  float bias = (side ? gb_c : gb_g)[0];

  float4 hv = *(const float4*)(h + lane*4);
  float4 w0 = *(const float4*)(v0 + lane*4);
  float4 w1 = *(const float4*)(v1 + lane*4);
  float4 w2 = *(const float4*)(v2 + lane*4);
  float4 w3 = *(const float4*)(v3 + lane*4);
  float4 w4 = *(const float4*)(gw + lane*4);

  float d0 = hv.x*w0.x + hv.y*w0.y + hv.z*w0.z + hv.w*w0.w;
  float d1 = hv.x*w1.x + hv.y*w1.y + hv.z*w1.z + hv.w*w1.w;
  float d2 = hv.x*w2.x + hv.y*w2.y + hv.z*w2.z + hv.w*w2.w;
  float d3 = hv.x*w3.x + hv.y*w3.y + hv.z*w3.z + hv.w*w3.w;
  float d4 = hv.x*w4.x + hv.y*w4.y + hv.z*w4.z + hv.w*w4.w;
  #pragma unroll
  for(int s=1;s<64;s<<=1){
    d0 += __shfl_xor(d0, s); d1 += __shfl_xor(d1, s); d2 += __shfl_xor(d2, s);
    d3 += __shfl_xor(d3, s); d4 += __shfl_xor(d4, s);
  }
  if(lane == 0){
    float gam = 1.f/(1.f + __expf(-(d4 + bias)));
    if(side == 0){
      sbuf[0*4096+row]=d0; sbuf[1*4096+row]=d1; sbuf[2*4096+row]=d2;
      sbuf[3*4096+row]=d3; sbuf[4*4096+row]=gam;
    } else {
      sbuf[5*4096+row]=d0; sbuf[6*4096+row]=d1; sbuf[8*4096+row]=d2;
      sbuf[7*4096+row]=d3; sbuf[9*4096+row]=gam;
    }
  }
}

// ---------------------------------------------------------------------------
// k_gat: O^T = V^T * P^T, P generated in-register as the MFMA B-operand.
// grid (64 ng, 2 kc, 4 modes) x 256 thr (4 waves: 2 kh x 2 ng).
// A staged in LDS (global_load_lds, double-buffered, 32KB/step) and SHARED
// by the ng waves; conflict-free ds_read_b128 (fragment in lane-read order).
// One barrier/step; staging issued at step top so exp+MFMA hides L2 latency.
// Masks in XOR-swizzled LDS; s2 register-prefetched. 80KB LDS -> 2 blocks/CU.
// ---------------------------------------------------------------------------
__global__ __launch_bounds__(256,2) void k_gat(
    const float* __restrict__ sbuf,
    const uint8_t* __restrict__ packbits, const uint8_t* __restrict__ bitsT,
    const u16* __restrict__ hTg, const u16* __restrict__ hTc,
    float* __restrict__ part, float* __restrict__ Zpart)
{
  const int mode = blockIdx.z;
  const int kc   = blockIdx.y;
  const int nodebase = blockIdx.x * 64;
  const int kcbase   = kc * 2048;

  const float* s1; const float* s2; const uint8_t* bits; const u16* hT;
  if(mode == 0){ s1 = sbuf;        s2 = sbuf+4096;   bits = packbits;           hT = hTg; }
  else if(mode == 1){ s1 = sbuf+2*4096; s2 = sbuf+7*4096; bits = packbits+4194304; hT = hTc; }
  else if(mode == 2){ s1 = sbuf+5*4096; s2 = sbuf+6*4096; bits = packbits+2097152; hT = hTc; }
  else { s1 = sbuf+8*4096; s2 = sbuf+3*4096; bits = bitsT; hT = hTg; }

  const int t = threadIdx.x, wid = t>>6, lane = t&63, lrow = lane&15, lhi = lane>>4;
  const int kh = wid >> 1;        // k-half of the 2048 chunk
  const int ng_sub = wid & 1;     // 32-node group

  __shared__ __align__(16) char U[81920];
  char* A_lds  = U;               // [2 dbuf][2 kh][16KB]
  char* mask_l = U + 65536;       // [64 rows][256B], 16B-slot XOR-swizzled

  // ---- prologue: stage masks (16KB, swizzled 16B slots) ----
  {
    int row = t>>2, seg = t&3;
    const char* g = (const char*)bits + (size_t)(nodebase+row)*512 + kc*256 + seg*64;
    char* drow_ = mask_l + row*256;
    #pragma unroll
    for(int i=0;i<4;i++){
      int slot = seg*4 + i;
      *(ulonglong2*)(drow_ + (((slot ^ (row&7)))<<4)) = *(const ulonglong2*)(g + i*16);
    }
  }
  // ---- prologue: stage A step 0 into buf0 (each wave: its kh, its half) ----
  const char* hTb = (const char*)hT;
  {
    const char* g = hTb + ((size_t)kc*64 + kh*32 + 0)*16384 + ng_sub*8192 + lane*16;
    char* l = A_lds + 0*32768 + kh*16384 + ng_sub*8192;
    #pragma unroll
    for(int i=0;i<8;i++) gl16(g + i*1024, l + i*1024);
  }
  // ---- per-wave global max over FULL s2 (no cross-wave reduce needed) ----
  float mxv = -1e30f;
  #pragma unroll
  for(int i=0;i<16;i++){
    float4 v = *(const float4*)(s2 + lane*64 + i*4);
    mxv = fmaxf(mxv, fmaxf(fmaxf(v.x,v.y), fmaxf(v.z,v.w)));
  }
  #pragma unroll
  for(int sh=1; sh<64; sh<<=1) mxv = fmaxf(mxv, __shfl_xor(mxv, sh));
  const float maxs2 = mxv;

  const int wnode = nodebase + ng_sub*32;
  const float L2E = 1.4426950408889634f;
  float c1[2], c2[2], z[2];
  #pragma unroll
  for(int nf=0; nf<2; nf++){
    float s1v = s1[wnode + nf*16 + lrow];
    float m = lk(s1v + maxs2);
    c1[nf] = (s1v - m)*L2E;
    c2[nf] = (0.2f*s1v - m)*L2E;
    z[nf] = 0.f;
  }

  f32x4 acc[16][2];
  const f32x4 zz = {0.f,0.f,0.f,0.f};
  #pragma unroll
  for(int i=0;i<16;i++){ acc[i][0]=zz; acc[i][1]=zz; }

  const float* s2g = s2 + kcbase + kh*1024 + lhi*8;
  const char* mrow0 = mask_l + (ng_sub*32 + lrow)*256;
  const char* mrow1 = mask_l + (ng_sub*32 + 16 + lrow)*256;
  const int mx0 = (ng_sub*32 + lrow) & 7, mx1 = (ng_sub*32 + 16 + lrow) & 7;

  // s2 register prefetch for step 0
  float4 csA = *(const float4*)(s2g);
  float4 csB = *(const float4*)(s2g + 4);

  __syncthreads();   // masks + A step0 staged (vmcnt drained)

  // ---- main loop: 32 steps, 1 barrier/step ----
  #pragma unroll 1
  for(int s=0; s<32; s++){
    const int cur = s & 1;
    // stage step s+1 into buf^1 (hidden under this step's compute)
    if(s < 31){
      const char* g = hTb + ((size_t)kc*64 + kh*32 + s + 1)*16384 + ng_sub*8192 + lane*16;
      char* l = A_lds + (cur^1)*32768 + kh*16384 + ng_sub*8192;
      #pragma unroll
      for(int i=0;i<8;i++) gl16(g + i*1024, l + i*1024);
    }
    float4 sA = csA, sB = csB;
    if(s < 31){
      csA = *(const float4*)(s2g + (s+1)*32);
      csB = *(const float4*)(s2g + (s+1)*32 + 4);
    }
    float e1[8], e2[8];
    {
      float sv[8] = {sA.x,sA.y,sA.z,sA.w,sB.x,sB.y,sB.z,sB.w};
      #pragma unroll
      for(int j=0;j<8;j++){ e1[j] = sv[j]*L2E; e2[j] = sv[j]*(0.2f*L2E); }
    }
    // mask words (swizzled slot): wb = kh*128 + s*4
    const int slot = kh*8 + (s>>2), win = (s&3)*4;
    u32 mw0 = *(const u32*)(mrow0 + ((slot ^ mx0)<<4) + win);
    u32 mw1 = *(const u32*)(mrow1 + ((slot ^ mx1)<<4) + win);
    short8 b[2];
    #pragma unroll
    for(int nf=0; nf<2; nf++){
      u32 mw = nf ? mw1 : mw0;
      u32 w4[4];
      #pragma unroll
      for(int pr=0; pr<4; pr++){
        float bit0 = (float)((mw >> (lhi*8 + 2*pr  )) & 1u);
        float bit1 = (float)((mw >> (lhi*8 + 2*pr+1)) & 1u);
        float p0 = __builtin_amdgcn_exp2f(fmaxf(c1[nf]+e1[2*pr  ], c2[nf]+e2[2*pr  ])) * bit0;
        float p1 = __builtin_amdgcn_exp2f(fmaxf(c1[nf]+e1[2*pr+1], c2[nf]+e2[2*pr+1])) * bit1;
        z[nf] += p0 + p1;
        u32 q0 = __float_as_uint(p0) + 0x8000u;
        u32 q1 = __float_as_uint(p1) + 0x8000u;
        w4[pr] = (q1 & 0xFFFF0000u) | (q0 >> 16);
      }
      union{ u32 u[4]; short8 s8; } cv;
      cv.u[0]=w4[0]; cv.u[1]=w4[1]; cv.u[2]=w4[2]; cv.u[3]=w4[3];
      b[nf] = cv.s8;
    }
    // A from LDS (conflict-free: lane reads byte lane*16 of each 1KB frag)
    const char* Af = A_lds + cur*32768 + kh*16384 + lane*16;
    #pragma unroll
    for(int mf=0; mf<16; mf++){
      short8 a = *(const short8*)(Af + mf*1024);
      acc[mf][0] = __builtin_amdgcn_mfma_f32_16x16x32_bf16(a, b[0], acc[mf][0], 0,0,0);
      acc[mf][1] = __builtin_amdgcn_mfma_f32_16x16x32_bf16(a, b[1], acc[mf][1], 0,0,0);
    }
    __syncthreads();   // protects buf reuse + completes s+1 staging
  }

  // ---- Z: reduce across lhi, write per-(kc,kh) slot; k_epi sums 4 ----
  #pragma unroll
  for(int nf=0; nf<2; nf++){
    z[nf] += __shfl_xor(z[nf], 16);
    z[nf] += __shfl_xor(z[nf], 32);
  }
  if(lhi == 0){
    float* zp = Zpart + (size_t)(mode*4 + kc*2 + kh)*4096 + wnode;
    zp[lrow]      = z[0];
    zp[16 + lrow] = z[1];
  }

  // ---- kh-reduce via 32KB swizzled LDS (two 8-mf rounds), then store ----
  __syncthreads();                 // loop done; A_lds free
  float* R = (float*)A_lds;        // [64 rows][128 f32], XOR-swizzled
  float* po = part + ((size_t)(mode*2 + kc) << 20);
  #pragma unroll
  for(int half=0; half<2; half++){
    if(kh == 1){
      #pragma unroll
      for(int mf8=0; mf8<8; mf8++){
        #pragma unroll
        for(int nf=0; nf<2; nf++){
          int r = ng_sub*32 + nf*16 + lrow;
          int byte_ = r*512 + ((mf8*64 + lhi*16) ^ ((r&7)<<4));
          *(f32x4*)((char*)R + byte_) = acc[half*8 + mf8][nf];
        }
      }
    }
    __syncthreads();
    if(kh == 0){
      #pragma unroll
      for(int mf8=0; mf8<8; mf8++){
        #pragma unroll
        for(int nf=0; nf<2; nf++){
          int r = ng_sub*32 + nf*16 + lrow;
          int byte_ = r*512 + ((mf8*64 + lhi*16) ^ ((r&7)<<4));
          f32x4 o = *(const f32x4*)((const char*)R + byte_);
          o = o + acc[half*8 + mf8][nf];
          int node = nodebase + r;
          *(f32x4*)(po + (size_t)node*256 + (half*8+mf8)*16 + lhi*4) = o;
        }
      }
    }
    __syncthreads();
  }
}

// ---------------------------------------------------------------------------
// k_epi: out = leaky(h + sum(A)/za + gamma*sum(B)/zb), fused kc/kh-reduce.
// ---------------------------------------------------------------------------
__global__ __launch_bounds__(256) void k_epi(
    const float* __restrict__ hg, const float* __restrict__ hc,
    const float* __restrict__ part, const float* __restrict__ Zpart,
    const float* __restrict__ sbuf, float* __restrict__ out)
{
  int idx = blockIdx.x*256 + threadIdx.x;   // 0..524287
  int fid = idx*4;
  int side = fid >> 20;
  int l = fid & 1048575;
  int node = l >> 8;
  int modeA = side ? 2 : 0, modeB = side ? 3 : 1;
  const float* h = side ? hc : hg;
  float gam = sbuf[(side ? 9 : 4)*4096 + node];
  float za = Zpart[(size_t)(modeA*4+0)*4096 + node] + Zpart[(size_t)(modeA*4+1)*4096 + node]
           + Zpart[(size_t)(modeA*4+2)*4096 + node] + Zpart[(size_t)(modeA*4+3)*4096 + node];
  float zb = Zpart[(size_t)(modeB*4+0)*4096 + node] + Zpart[(size_t)(modeB*4+1)*4096 + node]
           + Zpart[(size_t)(modeB*4+2)*4096 + node] + Zpart[(size_t)(modeB*4+3)*4096 + node];
  float rza = 1.f / fmaxf(za, 1e-30f);
  float rzb = 1.f / fmaxf(zb, 1e-30f);
  float4 a0 = *(const float4*)(part + ((size_t)(modeA*2  )<<20) + l);
  float4 a1 = *(const float4*)(part + ((size_t)(modeA*2+1)<<20) + l);
  float4 b0 = *(const float4*)(part + ((size_t)(modeB*2  )<<20) + l);
  float4 b1 = *(const float4*)(part + ((size_t)(modeB*2+1)<<20) + l);
  float4 h4 = *(const float4*)(h + l);
  float4 o;
  o.x = lk(h4.x + (a0.x+a1.x)*rza + gam*(b0.x+b1.x)*rzb);
  o.y = lk(h4.y + (a0.y+a1.y)*rza + gam*(b0.y+b1.y)*rzb);
  o.z = lk(h4.z + (a0.z+a1.z)*rza + gam*(b0.z+b1.z)*rzb);
  o.w = lk(h4.w + (a0.w+a1.w)*rza + gam*(b0.w+b1.w)*rzb);
  *(float4*)(out + fid) = o;
}

// ---------------------------------------------------------------------------
extern "C" void kernel_launch(void* const* d_in, const int* in_sizes, int n_in,
                              void* d_out, int out_size, void* d_ws, size_t ws_size,
                              hipStream_t stream)
{
  const float* gene_x   = (const float*)d_in[0];
  const float* cell_x   = (const float*)d_in[1];
  const float* gene_adj = (const float*)d_in[2];
  const float* cell_adj = (const float*)d_in[3];
  const float* gc_adj   = (const float*)d_in[4];
  const float* Wg       = (const float*)d_in[5];
  const float* Wc       = (const float*)d_in[6];
  const float* a_gg     = (const float*)d_in[7];
  const float* a_gc     = (const float*)d_in[8];
  const float* a_cc     = (const float*)d_in[9];
  const float* a_cg     = (const float*)d_in[10];
  const float* gw_g     = (const float*)d_in[11];
  const float* gb_g     = (const float*)d_in[12];
  const float* gw_c     = (const float*)d_in[13];
  const float* gb_c     = (const float*)d_in[14];

  char* ws = (char*)d_ws;
  float* hg   = (float*)(ws);                    // 4MB
  float* hc   = (float*)(ws + (4u<<20));         // 4MB
  u16*   hTg  = (u16*)  (ws + (8u<<20));         // 2MB (tiled)
  u16*   hTc  = (u16*)  (ws + (10u<<20));        // 2MB (tiled)
  float* sbuf = (float*)(ws + (12u<<20));        // 160KB
  float* Zpart= (float*)(ws + (12u<<20) + (512u<<10)); // 256KB (16 x 4096 f32)
  uint8_t* bitsT = (uint8_t*)(ws + (13u<<20));   // 2MB
  u16*   Wgbf = (u16*)  (ws + (17u<<20));        // 0.5MB (overlaps part; used pre-k_gat)
  u16*   Wcbf = (u16*)  (ws + (17u<<20) + (512u<<10));
  float* part = (float*)(ws + (17u<<20));        // 32MB: [mode][kc][node][d]; ends 49MB
  u64*   packbits = (u64*)(ws + (49u<<20));      // 6MB: gene, cell, gc; ends 55MB

  k_wcvt<<<dim3(128), 256, 0, stream>>>(Wg, Wc, Wgbf, Wcbf);
  k_pack<<<dim3(512), 256, 0, stream>>>(gene_adj, cell_adj, gc_adj, packbits);
  k_bitTT<<<dim3(1024), 256, 0, stream>>>(packbits + 524288, (u64*)bitsT);
  k_hgemm<<<dim3(64,2), 512, 0, stream>>>(gene_x, cell_x, Wgbf, Wcbf, hg, hc, hTg, hTc);
  k_svec<<<dim3(2048), 256, 0, stream>>>(hg, hc, a_gg, a_gc, a_cc, a_cg,
                                         gw_g, gb_g, gw_c, gb_c, sbuf);
  k_gat<<<dim3(64,2,4), 256, 0, stream>>>(sbuf, (const uint8_t*)packbits,
                                          bitsT, hTg, hTc, part, Zpart);
  k_epi<<<dim3(2048), 256, 0, stream>>>(hg, hc, part, Zpart, sbuf, (float*)d_out);
}

// Round 17
// 133.812 us; speedup vs baseline: 1.0745x; 1.0047x over previous
//
#include <hip/hip_runtime.h>
#include <stdint.h>

#define NGC 4096   // both node counts
#define FIN 512
#define DD  256

typedef __attribute__((ext_vector_type(8))) short short8;
typedef __attribute__((ext_vector_type(4))) float f32x4;
typedef unsigned short u16;
typedef unsigned int   u32;
typedef unsigned long long u64;

static __device__ __forceinline__ float bf2f(u16 u){ return __uint_as_float(((u32)u)<<16); }
static __device__ __forceinline__ u16 f2bf(float f){
  u32 u = __float_as_uint(f);
  u += 0x7fffu + ((u>>16)&1u);
  return (u16)(u>>16);
}
static __device__ __forceinline__ u64 pack4bf(f32x4 v){
  u64 r;
  r  = (u64)f2bf(v[0]);
  r |= (u64)f2bf(v[1]) << 16;
  r |= (u64)f2bf(v[2]) << 32;
  r |= (u64)f2bf(v[3]) << 48;
  return r;
}
static __device__ __forceinline__ float lk(float x){ return fmaxf(x, 0.2f*x); }
static __device__ __forceinline__ u64 shfl_xor64(u64 x, int m){
  u32 lo = (u32)x, hi = (u32)(x >> 32);
  lo = __shfl_xor(lo, m); hi = __shfl_xor(hi, m);
  return ((u64)hi << 32) | lo;
}
// spread 16 bits so bit i lands at position 4*i
static __device__ __forceinline__ u64 spread4(u64 x){
  x &= 0xFFFFull;
  x = (x | (x << 24)) & 0x000000FF000000FFull;
  x = (x | (x << 12)) & 0x000F000F000F000Full;
  x = (x | (x << 6))  & 0x0303030303030303ull;
  x = (x | (x << 3))  & 0x1111111111111111ull;
  return x;
}
// async global->LDS: lds dest = uniform base + lane*16; global src per-lane.
static __device__ __forceinline__ void gl16(const void* g, void* l){
  __builtin_amdgcn_global_load_lds(
    (const __attribute__((address_space(1))) void*)g,
    (__attribute__((address_space(3))) void*)l, 16, 0, 0);
}

// ---------------------------------------------------------------------------
// k_wcvt: W (f32) -> bf16 copies for the GEMM.
// ---------------------------------------------------------------------------
__global__ __launch_bounds__(256) void k_wcvt(
    const float* __restrict__ Wg, const float* __restrict__ Wc,
    u16* __restrict__ Wgbf, u16* __restrict__ Wcbf)
{
  int base = (blockIdx.x*256 + threadIdx.x)*4;   // grid 128 -> 131072 elems
  float4 a = *(const float4*)(Wg + base);
  float4 b = *(const float4*)(Wc + base);
  ushort4 oa, ob;
  oa.x=f2bf(a.x); oa.y=f2bf(a.y); oa.z=f2bf(a.z); oa.w=f2bf(a.w);
  ob.x=f2bf(b.x); ob.y=f2bf(b.y); ob.z=f2bf(b.z); ob.w=f2bf(b.w);
  *(ushort4*)(Wgbf + base) = oa;
  *(ushort4*)(Wcbf + base) = ob;
}

// ---------------------------------------------------------------------------
// k_pack: bit-pack 3 adjacency matrices (f32 0/1 -> 1 bit), PLAIN layout:
// bit k of row r at u64 word [r*64 + k/64]. PERSISTENT waves: 2048 waves x
// 6 rows each, register double-buffered. NOTE: four structurally different
// variants (r13-r16) all land at ~71-74us -> this 192MB read runs at the
// platform's effective read ceiling (~2.7 TB/s incl. L3 hits). Do not
// re-attack without new evidence.
// ---------------------------------------------------------------------------
__global__ __launch_bounds__(256) void k_pack(
    const float* __restrict__ gene_adj, const float* __restrict__ cell_adj,
    const float* __restrict__ gc_adj,   u64* __restrict__ packbits)
{
  int t = threadIdx.x, wid = t>>6, lane = t&63;
  int w = blockIdx.x*4 + wid;           // 0..2047
  int row0 = w*6;
  const int sel = lane >> 2;
  const int sh = (lane & 3) * 16;

  float4 bufA[16], bufB[16];

  // prologue: load row0 into bufA
  {
    int m = row0 >> 12;
    const float* sp = (m==0) ? gene_adj : (m==1) ? cell_adj : gc_adj;
    const float* rp = sp + (size_t)(row0 & 4095)*NGC + lane*4;
    #pragma unroll
    for(int j=0;j<16;j++) bufA[j] = *(const float4*)(rp + j*256);
  }

  #pragma unroll
  for(int i=0;i<6;i++){
    const bool evn = (i & 1) == 0;
    // issue next row's loads into the other buffer
    if(i < 5){
      int row = row0 + i + 1;
      int m = row >> 12;
      const float* sp = (m==0) ? gene_adj : (m==1) ? cell_adj : gc_adj;
      const float* rp = sp + (size_t)(row & 4095)*NGC + lane*4;
      if(evn){
        #pragma unroll
        for(int j=0;j<16;j++) bufB[j] = *(const float4*)(rp + j*256);
      } else {
        #pragma unroll
        for(int j=0;j<16;j++) bufA[j] = *(const float4*)(rp + j*256);
      }
    }
    // ballots on current buffer
    u64 k0=0, k1=0, k2=0, k3=0;
    #pragma unroll
    for(int j=0;j<16;j++){
      float4 v = evn ? bufA[j] : bufB[j];
      u64 b0 = __ballot(v.x != 0.0f);
      u64 b1 = __ballot(v.y != 0.0f);
      u64 b2 = __ballot(v.z != 0.0f);
      u64 b3 = __ballot(v.w != 0.0f);
      if(sel == j){ k0=b0; k1=b1; k2=b2; k3=b3; }
    }
    u64 wv = spread4(k0 >> sh) | (spread4(k1 >> sh) << 1)
           | (spread4(k2 >> sh) << 2) | (spread4(k3 >> sh) << 3);
    int row = row0 + i;
    packbits[((size_t)(row >> 12) << 18) + (size_t)(row & 4095)*64 + lane] = wv;
  }
}

// ---------------------------------------------------------------------------
// k_bitTT: transpose gc bits -> bitsT (both PLAIN layout, u64 load/store).
// One wave per 64x64-bit tile; 4096 tiles; 4 waves/block -> 1024 blocks.
// ---------------------------------------------------------------------------
__global__ __launch_bounds__(256) void k_bitTT(
    const u64* __restrict__ gcb, u64* __restrict__ bT)
{
  int t = threadIdx.x, wid = t>>6, lane = t&63;
  int id = blockIdx.x*4 + wid;          // 0..4095
  int G = id & 63, C = id >> 6;

  u64 x = gcb[(size_t)(64*G + lane)*64 + C];

  const u64 M1  = 0xAAAAAAAAAAAAAAAAull;
  const u64 M2  = 0xCCCCCCCCCCCCCCCCull;
  const u64 M4  = 0xF0F0F0F0F0F0F0F0ull;
  const u64 M8  = 0xFF00FF00FF00FF00ull;
  const u64 M16 = 0xFFFF0000FFFF0000ull;
  const u64 M32 = 0xFFFFFFFF00000000ull;
  #define TSTEP(S, M) { u64 y = shfl_xor64(x, S); \
    x = (lane & S) ? ((x & (M)) | ((y >> S) & ~(M))) \
                   : ((x & ~(M)) | ((y << S) & (M))); }
  TSTEP(32, M32) TSTEP(16, M16) TSTEP(8, M8)
  TSTEP(4,  M4)  TSTEP(2,  M2)  TSTEP(1, M1)
  #undef TSTEP

  bT[(size_t)(64*C + lane)*64 + G] = x;
}

// ---------------------------------------------------------------------------
// k_hgemm: h = x @ W.T  (f32 x in -> bf16 staged, f32 h out + TILED bf16 hT)
// hTt layout: [kblock=k/32][dtile=d/16][kgrp=(k&31)/8][drow=d&15][k&7] so one
// MFMA A-fragment (16 d x 32 k = 1KB) is contiguous IN LANE-READ ORDER:
// lane (lrow,lhi) reads 16B at byte lhi*256+lrow*16 = lane*16.
// grid (64 row-tiles, 2 sides), 512 threads (8 waves). BM=64, BK=64, N=256.
// ---------------------------------------------------------------------------
__global__ __launch_bounds__(512) void k_hgemm(
    const float* __restrict__ xg, const float* __restrict__ xc,
    const u16* __restrict__ Wg, const u16* __restrict__ Wc,
    float* __restrict__ hg, float* __restrict__ hc,
    u16* __restrict__ hTg, u16* __restrict__ hTc)
{
  const int side = blockIdx.y;
  const float* x = side ? xc : xg;
  const u16* W = side ? Wc : Wg;
  float* h  = side ? hc : hg;
  u16*  hT  = side ? hTc : hTg;
  const int r0 = blockIdx.x * 64;
  const int t = threadIdx.x;
  const int wid = t >> 6, lane = t & 63;
  const int lrow = lane & 15, lhi = lane >> 4;

  __shared__ __align__(16) char smem[32768];

  f32x4 acc[4][2];
  const f32x4 z4 = {0.f,0.f,0.f,0.f};
  #pragma unroll
  for(int i=0;i<4;i++){ acc[i][0]=z4; acc[i][1]=z4; }

  const int r = t >> 3, c8 = t & 7;
  for(int k0 = 0; k0 < FIN; k0 += 64){
    const float* xp = x + (size_t)(r0 + r)*FIN + k0 + c8*8;
    float4 xa = *(const float4*)xp;
    float4 xb = *(const float4*)(xp + 4);
    short8 xv;
    xv[0]=(short)f2bf(xa.x); xv[1]=(short)f2bf(xa.y);
    xv[2]=(short)f2bf(xa.z); xv[3]=(short)f2bf(xa.w);
    xv[4]=(short)f2bf(xb.x); xv[5]=(short)f2bf(xb.y);
    xv[6]=(short)f2bf(xb.z); xv[7]=(short)f2bf(xb.w);
    int wbyte = r*128 + (((c8 ^ (r & 7)) & 7) << 4);
    *(short8*)(smem + wbyte) = xv;
    __syncthreads();
    #pragma unroll
    for(int ksub = 0; ksub < 2; ksub++){
      short8 b[2];
      #pragma unroll
      for(int nf=0; nf<2; nf++){
        int n = wid*32 + nf*16 + lrow;
        b[nf] = *(const short8*)(W + (size_t)n*FIN + k0 + ksub*32 + lhi*8);
      }
      #pragma unroll
      for(int mf=0; mf<4; mf++){
        int row = mf*16 + lrow;
        int g = ksub*4 + lhi;
        short8 a = *(const short8*)(smem + row*128 + (((g ^ (row & 7)) & 7) << 4));
        #pragma unroll
        for(int nf=0; nf<2; nf++)
          acc[mf][nf] = __builtin_amdgcn_mfma_f32_16x16x32_bf16(a, b[nf], acc[mf][nf], 0,0,0);
      }
    }
    __syncthreads();
  }
  // write h (f32) and stage bf16 transpose in LDS
  #pragma unroll
  for(int mf=0; mf<4; mf++){
    #pragma unroll
    for(int nf=0; nf<2; nf++){
      int col = wid*32 + nf*16 + lrow;
      #pragma unroll
      for(int j=0;j<4;j++){
        int row = mf*16 + lhi*4 + j;
        float v = acc[mf][nf][j];
        h[(size_t)(r0+row)*DD + col] = v;
        int byte_ = col*128 + (((row*2) ^ ((col & 7)<<4)));
        *(u16*)(smem + byte_) = f2bf(v);
      }
    }
  }
  __syncthreads();
  { // tiled hT store (read-order layout): thread -> (n = t>>1 d-row, half)
    int n = t >> 1, half = t & 1;
    #pragma unroll
    for(int gi=0; gi<4; gi++){
      int g = half*4 + gi;
      int byte_ = n*128 + (((g ^ (n & 7)) & 7) << 4);
      short8 v = *(const short8*)(smem + byte_);
      int kcol = r0 + g*8;   // global k (node) index, 8-aligned
      size_t off = (size_t)(kcol>>5)*8192 + (size_t)(n>>4)*512
                 + ((kcol>>3)&3)*128 + (n&15)*8;
      *(short8*)(hT + off) = v;
    }
  }
}

// ---------------------------------------------------------------------------
// k_svec: per-row dot products with attention vectors + gate sigmoid.
// sbuf layout (each 4096 f32):
// 0 s1gg 1 s2gg 2 s1gc 3 s2cg 4 gam_g 5 s1cc 6 s2cc 7 s2gc 8 s1cg 9 gam_c
// ---------------------------------------------------------------------------
__global__ __launch_bounds__(256) void k_svec(
    const float* __restrict__ hg, const float* __restrict__ hc,
    const float* __restrict__ a_gg, const float* __restrict__ a_gc,
    const float* __restrict__ a_cc, const float* __restrict__ a_cg,
    const float* __restrict__ gw_g, const float* __restrict__ gb_g,
    const float* __restrict__ gw_c, const float* __restrict__ gb_c,
    float* __restrict__ sbuf)
{
  int t = threadIdx.x, wid = t>>6, lane = t&63;
  int idx = blockIdx.x * 4 + wid;          // 0..8191
  int side = idx >> 12;
  int row  = idx & 4095;
  const float* h = (side ? hc : hg) + (size_t)row*DD;
  const float* v0 = (side ? a_cc : a_gg);        // same-type s1 half
  const float* v1 = (side ? a_cc : a_gg) + DD;   // same-type s2 half
  const float* v2 = (side ? a_cg : a_gc);        // cross s1 (this node as src)
  const float* v3 = (side ? a_gc : a_cg) + DD;   // cross s2 (this node as dst)
  const float* gw = side ? gw_c : gw_g;
  float bias = (side ? gb_c : gb_g)[0];

  float4 hv = *(const float4*)(h + lane*4);
  float4 w0 = *(const float4*)(v0 + lane*4);
  float4 w1 = *(const float4*)(v1 + lane*4);
  float4 w2 = *(const float4*)(v2 + lane*4);
  float4 w3 = *(const float4*)(v3 + lane*4);
  float4 w4 = *(const float4*)(gw + lane*4);

  float d0 = hv.x*w0.x + hv.y*w0.y + hv.z*w0.z + hv.w*w0.w;
  float d1 = hv.x*w1.x + hv.y*w1.y + hv.z*w1.z + hv.w*w1.w;
  float d2 = hv.x*w2.x + hv.y*w2.y + hv.z*w2.z + hv.w*w2.w;
  float d3 = hv.x*w3.x + hv.y*w3.y + hv.z*w3.z + hv.w*w3.w;
  float d4 = hv.x*w4.x + hv.y*w4.y + hv.z*w4.z + hv.w*w4.w;
  #pragma unroll
  for(int s=1;s<64;s<<=1){
    d0 += __shfl_xor(d0, s); d1 += __shfl_xor(d1, s); d2 += __shfl_xor(d2, s);
    d3 += __shfl_xor(d3, s); d4 += __shfl_xor(d4, s);
  }
  if(lane == 0){
    float gam = 1.f/(1.f + __expf(-(d4 + bias)));
    if(side == 0){
      sbuf[0*4096+row]=d0; sbuf[1*4096+row]=d1; sbuf[2*4096+row]=d2;
      sbuf[3*4096+row]=d3; sbuf[4*4096+row]=gam;
    } else {
      sbuf[5*4096+row]=d0; sbuf[6*4096+row]=d1; sbuf[8*4096+row]=d2;
      sbuf[7*4096+row]=d3; sbuf[9*4096+row]=gam;
    }
  }
}

// ---------------------------------------------------------------------------
// k_gat: O^T = V^T * P^T, P generated in-register as the MFMA B-operand.
// grid (64 ng, 2 kc, 4 modes) x 256 thr (4 waves: 2 kh x 2 ng).
// A staged in LDS (global_load_lds, double-buffered, 32KB/step) and SHARED
// by the ng waves; conflict-free ds_read_b128 (fragment in lane-read order).
// One barrier/step; staging issued at step top so exp+MFMA hides L2 latency.
// Masks in XOR-swizzled LDS; s2 register-prefetched. 80KB LDS -> 2 blocks/CU.
// part stored as bf16 (halves store + epi-read traffic).
// ---------------------------------------------------------------------------
__global__ __launch_bounds__(256,2) void k_gat(
    const float* __restrict__ sbuf,
    const uint8_t* __restrict__ packbits, const uint8_t* __restrict__ bitsT,
    const u16* __restrict__ hTg, const u16* __restrict__ hTc,
    u16* __restrict__ part, float* __restrict__ Zpart)
{
  const int mode = blockIdx.z;
  const int kc   = blockIdx.y;
  const int nodebase = blockIdx.x * 64;
  const int kcbase   = kc * 2048;

  const float* s1; const float* s2; const uint8_t* bits; const u16* hT;
  if(mode == 0){ s1 = sbuf;        s2 = sbuf+4096;   bits = packbits;           hT = hTg; }
  else if(mode == 1){ s1 = sbuf+2*4096; s2 = sbuf+7*4096; bits = packbits+4194304; hT = hTc; }
  else if(mode == 2){ s1 = sbuf+5*4096; s2 = sbuf+6*4096; bits = packbits+2097152; hT = hTc; }
  else { s1 = sbuf+8*4096; s2 = sbuf+3*4096; bits = bitsT; hT = hTg; }

  const int t = threadIdx.x, wid = t>>6, lane = t&63, lrow = lane&15, lhi = lane>>4;
  const int kh = wid >> 1;        // k-half of the 2048 chunk
  const int ng_sub = wid & 1;     // 32-node group

  __shared__ __align__(16) char U[81920];
  char* A_lds  = U;               // [2 dbuf][2 kh][16KB]
  char* mask_l = U + 65536;       // [64 rows][256B], 16B-slot XOR-swizzled

  // ---- prologue: stage masks (16KB, swizzled 16B slots) ----
  {
    int row = t>>2, seg = t&3;
    const char* g = (const char*)bits + (size_t)(nodebase+row)*512 + kc*256 + seg*64;
    char* drow_ = mask_l + row*256;
    #pragma unroll
    for(int i=0;i<4;i++){
      int slot = seg*4 + i;
      *(ulonglong2*)(drow_ + (((slot ^ (row&7)))<<4)) = *(const ulonglong2*)(g + i*16);
    }
  }
  // ---- prologue: stage A step 0 into buf0 (each wave: its kh, its half) ----
  const char* hTb = (const char*)hT;
  {
    const char* g = hTb + ((size_t)kc*64 + kh*32 + 0)*16384 + ng_sub*8192 + lane*16;
    char* l = A_lds + 0*32768 + kh*16384 + ng_sub*8192;
    #pragma unroll
    for(int i=0;i<8;i++) gl16(g + i*1024, l + i*1024);
  }
  // ---- per-wave global max over FULL s2 (no cross-wave reduce needed) ----
  float mxv = -1e30f;
  #pragma unroll
  for(int i=0;i<16;i++){
    float4 v = *(const float4*)(s2 + lane*64 + i*4);
    mxv = fmaxf(mxv, fmaxf(fmaxf(v.x,v.y), fmaxf(v.z,v.w)));
  }
  #pragma unroll
  for(int sh=1; sh<64; sh<<=1) mxv = fmaxf(mxv, __shfl_xor(mxv, sh));
  const float maxs2 = mxv;

  const int wnode = nodebase + ng_sub*32;
  const float L2E = 1.4426950408889634f;
  float c1[2], c2[2], z[2];
  #pragma unroll
  for(int nf=0; nf<2; nf++){
    float s1v = s1[wnode + nf*16 + lrow];
    float m = lk(s1v + maxs2);
    c1[nf] = (s1v - m)*L2E;
    c2[nf] = (0.2f*s1v - m)*L2E;
    z[nf] = 0.f;
  }

  f32x4 acc[16][2];
  const f32x4 zz = {0.f,0.f,0.f,0.f};
  #pragma unroll
  for(int i=0;i<16;i++){ acc[i][0]=zz; acc[i][1]=zz; }

  const float* s2g = s2 + kcbase + kh*1024 + lhi*8;
  const char* mrow0 = mask_l + (ng_sub*32 + lrow)*256;
  const char* mrow1 = mask_l + (ng_sub*32 + 16 + lrow)*256;
  const int mx0 = (ng_sub*32 + lrow) & 7, mx1 = (ng_sub*32 + 16 + lrow) & 7;

  // s2 register prefetch for step 0
  float4 csA = *(const float4*)(s2g);
  float4 csB = *(const float4*)(s2g + 4);

  __syncthreads();   // masks + A step0 staged (vmcnt drained)

  // ---- main loop: 32 steps, 1 barrier/step ----
  #pragma unroll 1
  for(int s=0; s<32; s++){
    const int cur = s & 1;
    // stage step s+1 into buf^1 (hidden under this step's compute)
    if(s < 31){
      const char* g = hTb + ((size_t)kc*64 + kh*32 + s + 1)*16384 + ng_sub*8192 + lane*16;
      char* l = A_lds + (cur^1)*32768 + kh*16384 + ng_sub*8192;
      #pragma unroll
      for(int i=0;i<8;i++) gl16(g + i*1024, l + i*1024);
    }
    float4 sA = csA, sB = csB;
    if(s < 31){
      csA = *(const float4*)(s2g + (s+1)*32);
      csB = *(const float4*)(s2g + (s+1)*32 + 4);
    }
    float e1[8], e2[8];
    {
      float sv[8] = {sA.x,sA.y,sA.z,sA.w,sB.x,sB.y,sB.z,sB.w};
      #pragma unroll
      for(int j=0;j<8;j++){ e1[j] = sv[j]*L2E; e2[j] = sv[j]*(0.2f*L2E); }
    }
    // mask words (swizzled slot): wb = kh*128 + s*4
    const int slot = kh*8 + (s>>2), win = (s&3)*4;
    u32 mw0 = *(const u32*)(mrow0 + ((slot ^ mx0)<<4) + win);
    u32 mw1 = *(const u32*)(mrow1 + ((slot ^ mx1)<<4) + win);
    short8 b[2];
    #pragma unroll
    for(int nf=0; nf<2; nf++){
      u32 mw = nf ? mw1 : mw0;
      u32 w4[4];
      #pragma unroll
      for(int pr=0; pr<4; pr++){
        float bit0 = (float)((mw >> (lhi*8 + 2*pr  )) & 1u);
        float bit1 = (float)((mw >> (lhi*8 + 2*pr+1)) & 1u);
        float p0 = __builtin_amdgcn_exp2f(fmaxf(c1[nf]+e1[2*pr  ], c2[nf]+e2[2*pr  ])) * bit0;
        float p1 = __builtin_amdgcn_exp2f(fmaxf(c1[nf]+e1[2*pr+1], c2[nf]+e2[2*pr+1])) * bit1;
        z[nf] += p0 + p1;
        u32 q0 = __float_as_uint(p0) + 0x8000u;
        u32 q1 = __float_as_uint(p1) + 0x8000u;
        w4[pr] = (q1 & 0xFFFF0000u) | (q0 >> 16);
      }
      union{ u32 u[4]; short8 s8; } cv;
      cv.u[0]=w4[0]; cv.u[1]=w4[1]; cv.u[2]=w4[2]; cv.u[3]=w4[3];
      b[nf] = cv.s8;
    }
    // A from LDS (conflict-free: lane reads byte lane*16 of each 1KB frag)
    const char* Af = A_lds + cur*32768 + kh*16384 + lane*16;
    #pragma unroll
    for(int mf=0; mf<16; mf++){
      short8 a = *(const short8*)(Af + mf*1024);
      acc[mf][0] = __builtin_amdgcn_mfma_f32_16x16x32_bf16(a, b[0], acc[mf][0], 0,0,0);
      acc[mf][1] = __builtin_amdgcn_mfma_f32_16x16x32_bf16(a, b[1], acc[mf][1], 0,0,0);
    }
    __syncthreads();   // protects buf reuse + completes s+1 staging
  }

  // ---- Z: reduce across lhi, write per-(kc,kh) slot; k_epi sums 4 ----
  #pragma unroll
  for(int nf=0; nf<2; nf++){
    z[nf] += __shfl_xor(z[nf], 16);
    z[nf] += __shfl_xor(z[nf], 32);
  }
  if(lhi == 0){
    float* zp = Zpart + (size_t)(mode*4 + kc*2 + kh)*4096 + wnode;
    zp[lrow]      = z[0];
    zp[16 + lrow] = z[1];
  }

  // ---- kh-reduce via 32KB swizzled LDS (two 8-mf rounds), bf16 store ----
  __syncthreads();                 // loop done; A_lds free
  float* R = (float*)A_lds;        // [64 rows][128 f32], XOR-swizzled
  u16* po = part + ((size_t)(mode*2 + kc) << 20);
  #pragma unroll
  for(int half=0; half<2; half++){
    if(kh == 1){
      #pragma unroll
      for(int mf8=0; mf8<8; mf8++){
        #pragma unroll
        for(int nf=0; nf<2; nf++){
          int r = ng_sub*32 + nf*16 + lrow;
          int byte_ = r*512 + ((mf8*64 + lhi*16) ^ ((r&7)<<4));
          *(f32x4*)((char*)R + byte_) = acc[half*8 + mf8][nf];
        }
      }
    }
    __syncthreads();
    if(kh == 0){
      #pragma unroll
      for(int mf8=0; mf8<8; mf8++){
        #pragma unroll
        for(int nf=0; nf<2; nf++){
          int r = ng_sub*32 + nf*16 + lrow;
          int byte_ = r*512 + ((mf8*64 + lhi*16) ^ ((r&7)<<4));
          f32x4 o = *(const f32x4*)((const char*)R + byte_);
          o = o + acc[half*8 + mf8][nf];
          int node = nodebase + r;
          *(u64*)(po + (size_t)node*256 + (half*8+mf8)*16 + lhi*4) = pack4bf(o);
        }
      }
    }
    __syncthreads();
  }
}

// ---------------------------------------------------------------------------
// k_epi: out = leaky(h + sum(A)/za + gamma*sum(B)/zb), fused kc/kh-reduce.
// part is bf16.
// ---------------------------------------------------------------------------
__global__ __launch_bounds__(256) void k_epi(
    const float* __restrict__ hg, const float* __restrict__ hc,
    const u16* __restrict__ part, const float* __restrict__ Zpart,
    const float* __restrict__ sbuf, float* __restrict__ out)
{
  int idx = blockIdx.x*256 + threadIdx.x;   // 0..524287
  int fid = idx*4;
  int side = fid >> 20;
  int l = fid & 1048575;
  int node = l >> 8;
  int modeA = side ? 2 : 0, modeB = side ? 3 : 1;
  const float* h = side ? hc : hg;
  float gam = sbuf[(side ? 9 : 4)*4096 + node];
  float za = Zpart[(size_t)(modeA*4+0)*4096 + node] + Zpart[(size_t)(modeA*4+1)*4096 + node]
           + Zpart[(size_t)(modeA*4+2)*4096 + node] + Zpart[(size_t)(modeA*4+3)*4096 + node];
  float zb = Zpart[(size_t)(modeB*4+0)*4096 + node] + Zpart[(size_t)(modeB*4+1)*4096 + node]
           + Zpart[(size_t)(modeB*4+2)*4096 + node] + Zpart[(size_t)(modeB*4+3)*4096 + node];
  float rza = 1.f / fmaxf(za, 1e-30f);
  float rzb = 1.f / fmaxf(zb, 1e-30f);
  ushort4 a0 = *(const ushort4*)(part + ((size_t)(modeA*2  )<<20) + l);
  ushort4 a1 = *(const ushort4*)(part + ((size_t)(modeA*2+1)<<20) + l);
  ushort4 b0 = *(const ushort4*)(part + ((size_t)(modeB*2  )<<20) + l);
  ushort4 b1 = *(const ushort4*)(part + ((size_t)(modeB*2+1)<<20) + l);
  float4 h4 = *(const float4*)(h + l);
  float4 o;
  o.x = lk(h4.x + (bf2f(a0.x)+bf2f(a1.x))*rza + gam*(bf2f(b0.x)+bf2f(b1.x))*rzb);
  o.y = lk(h4.y + (bf2f(a0.y)+bf2f(a1.y))*rza + gam*(bf2f(b0.y)+bf2f(b1.y))*rzb);
  o.z = lk(h4.z + (bf2f(a0.z)+bf2f(a1.z))*rza + gam*(bf2f(b0.z)+bf2f(b1.z))*rzb);
  o.w = lk(h4.w + (bf2f(a0.w)+bf2f(a1.w))*rza + gam*(bf2f(b0.w)+bf2f(b1.w))*rzb);
  *(float4*)(out + fid) = o;
}

// ---------------------------------------------------------------------------
extern "C" void kernel_launch(void* const* d_in, const int* in_sizes, int n_in,
                              void* d_out, int out_size, void* d_ws, size_t ws_size,
                              hipStream_t stream)
{
  const float* gene_x   = (const float*)d_in[0];
  const float* cell_x   = (const float*)d_in[1];
  const float* gene_adj = (const float*)d_in[2];
  const float* cell_adj = (const float*)d_in[3];
  const float* gc_adj   = (const float*)d_in[4];
  const float* Wg       = (const float*)d_in[5];
  const float* Wc       = (const float*)d_in[6];
  const float* a_gg     = (const float*)d_in[7];
  const float* a_gc     = (const float*)d_in[8];
  const float* a_cc     = (const float*)d_in[9];
  const float* a_cg     = (const float*)d_in[10];
  const float* gw_g     = (const float*)d_in[11];
  const float* gb_g     = (const float*)d_in[12];
  const float* gw_c     = (const float*)d_in[13];
  const float* gb_c     = (const float*)d_in[14];

  char* ws = (char*)d_ws;
  float* hg   = (float*)(ws);                    // 4MB
  float* hc   = (float*)(ws + (4u<<20));         // 4MB
  u16*   hTg  = (u16*)  (ws + (8u<<20));         // 2MB (tiled)
  u16*   hTc  = (u16*)  (ws + (10u<<20));        // 2MB (tiled)
  float* sbuf = (float*)(ws + (12u<<20));        // 160KB
  float* Zpart= (float*)(ws + (12u<<20) + (512u<<10)); // 256KB (16 x 4096 f32)
  uint8_t* bitsT = (uint8_t*)(ws + (13u<<20));   // 2MB
  u16*   Wgbf = (u16*)  (ws + (17u<<20));        // 0.5MB (overlaps part; used pre-k_gat)
  u16*   Wcbf = (u16*)  (ws + (17u<<20) + (512u<<10));
  u16*   part = (u16*)  (ws + (17u<<20));        // 16MB bf16: [mode][kc][node][d]
  u64*   packbits = (u64*)(ws + (49u<<20));      // 6MB: gene, cell, gc; ends 55MB

  k_wcvt<<<dim3(128), 256, 0, stream>>>(Wg, Wc, Wgbf, Wcbf);
  k_pack<<<dim3(512), 256, 0, stream>>>(gene_adj, cell_adj, gc_adj, packbits);
  k_bitTT<<<dim3(1024), 256, 0, stream>>>(packbits + 524288, (u64*)bitsT);
  k_hgemm<<<dim3(64,2), 512, 0, stream>>>(gene_x, cell_x, Wgbf, Wcbf, hg, hc, hTg, hTc);
  k_svec<<<dim3(2048), 256, 0, stream>>>(hg, hc, a_gg, a_gc, a_cc, a_cg,
                                         gw_g, gb_g, gw_c, gb_c, sbuf);
  k_gat<<<dim3(64,2,4), 256, 0, stream>>>(sbuf, (const uint8_t*)packbits,
                                          bitsT, hTg, hTc, part, Zpart);
  k_epi<<<dim3(2048), 256, 0, stream>>>(hg, hc, part, Zpart, sbuf, (float*)d_out);
}

// Round 18
// 132.413 us; speedup vs baseline: 1.0858x; 1.0106x over previous
//
#include <hip/hip_runtime.h>
#include <stdint.h>

#define NGC 4096   // both node counts
#define FIN 512
#define DD  256

typedef __attribute__((ext_vector_type(8))) short short8;
typedef __attribute__((ext_vector_type(4))) float f32x4;
typedef unsigned short u16;
typedef unsigned int   u32;
typedef unsigned long long u64;

static __device__ __forceinline__ float bf2f(u16 u){ return __uint_as_float(((u32)u)<<16); }
static __device__ __forceinline__ u16 f2bf(float f){
  u32 u = __float_as_uint(f);
  u += 0x7fffu + ((u>>16)&1u);
  return (u16)(u>>16);
}
static __device__ __forceinline__ u64 pack4bf(f32x4 v){
  u64 r;
  r  = (u64)f2bf(v[0]);
  r |= (u64)f2bf(v[1]) << 16;
  r |= (u64)f2bf(v[2]) << 32;
  r |= (u64)f2bf(v[3]) << 48;
  return r;
}
static __device__ __forceinline__ float lk(float x){ return fmaxf(x, 0.2f*x); }
static __device__ __forceinline__ u64 shfl_xor64(u64 x, int m){
  u32 lo = (u32)x, hi = (u32)(x >> 32);
  lo = __shfl_xor(lo, m); hi = __shfl_xor(hi, m);
  return ((u64)hi << 32) | lo;
}
// spread 16 bits so bit i lands at position 4*i
static __device__ __forceinline__ u64 spread4(u64 x){
  x &= 0xFFFFull;
  x = (x | (x << 24)) & 0x000000FF000000FFull;
  x = (x | (x << 12)) & 0x000F000F000F000Full;
  x = (x | (x << 6))  & 0x0303030303030303ull;
  x = (x | (x << 3))  & 0x1111111111111111ull;
  return x;
}
// async global->LDS: lds dest = uniform base + lane*16; global src per-lane.
static __device__ __forceinline__ void gl16(const void* g, void* l){
  __builtin_amdgcn_global_load_lds(
    (const __attribute__((address_space(1))) void*)g,
    (__attribute__((address_space(3))) void*)l, 16, 0, 0);
}

// ---------------------------------------------------------------------------
// k_front: FUSED independent front-end. Blocks 0..255: bit-pack the 3
// adjacency matrices (persistent waves, 8 waves x 6 rows each, register
// double-buffered -- pinned at the read-path ceiling ~72us over r13-r17).
// Blocks 256..383: h = x @ W.T with INLINE f32->bf16 W conversion
// (replaces k_wcvt + k_hgemm). The hgemm compute hides under the pack's
// memory-bound time; both paths are co-resident.
// ---------------------------------------------------------------------------
__global__ __launch_bounds__(512) void k_front(
    const float* __restrict__ gene_adj, const float* __restrict__ cell_adj,
    const float* __restrict__ gc_adj,   u64* __restrict__ packbits,
    const float* __restrict__ xg, const float* __restrict__ xc,
    const float* __restrict__ Wgf, const float* __restrict__ Wcf,
    float* __restrict__ hg, float* __restrict__ hc,
    u16* __restrict__ hTg, u16* __restrict__ hTc)
{
  __shared__ __align__(16) char smem[32768];
  const int t = threadIdx.x;
  const int wid = t >> 6, lane = t & 63;

  if(blockIdx.x < 256){
    // ---------------- pack path ----------------
    int w = blockIdx.x*8 + wid;           // 0..2047
    int row0 = w*6;
    const int sel = lane >> 2;
    const int sh = (lane & 3) * 16;

    float4 bufA[16], bufB[16];
    {
      int m = row0 >> 12;
      const float* sp = (m==0) ? gene_adj : (m==1) ? cell_adj : gc_adj;
      const float* rp = sp + (size_t)(row0 & 4095)*NGC + lane*4;
      #pragma unroll
      for(int j=0;j<16;j++) bufA[j] = *(const float4*)(rp + j*256);
    }
    #pragma unroll
    for(int i=0;i<6;i++){
      const bool evn = (i & 1) == 0;
      if(i < 5){
        int row = row0 + i + 1;
        int m = row >> 12;
        const float* sp = (m==0) ? gene_adj : (m==1) ? cell_adj : gc_adj;
        const float* rp = sp + (size_t)(row & 4095)*NGC + lane*4;
        if(evn){
          #pragma unroll
          for(int j=0;j<16;j++) bufB[j] = *(const float4*)(rp + j*256);
        } else {
          #pragma unroll
          for(int j=0;j<16;j++) bufA[j] = *(const float4*)(rp + j*256);
        }
      }
      u64 k0=0, k1=0, k2=0, k3=0;
      #pragma unroll
      for(int j=0;j<16;j++){
        float4 v = evn ? bufA[j] : bufB[j];
        u64 b0 = __ballot(v.x != 0.0f);
        u64 b1 = __ballot(v.y != 0.0f);
        u64 b2 = __ballot(v.z != 0.0f);
        u64 b3 = __ballot(v.w != 0.0f);
        if(sel == j){ k0=b0; k1=b1; k2=b2; k3=b3; }
      }
      u64 wv = spread4(k0 >> sh) | (spread4(k1 >> sh) << 1)
             | (spread4(k2 >> sh) << 2) | (spread4(k3 >> sh) << 3);
      int row = row0 + i;
      packbits[((size_t)(row >> 12) << 18) + (size_t)(row & 4095)*64 + lane] = wv;
    }
    return;
  }

  // ---------------- hgemm path ----------------
  const int bid = blockIdx.x - 256;       // 0..127
  const int side = bid >> 6;
  const float* x = side ? xc : xg;
  const float* Wf = side ? Wcf : Wgf;
  float* h  = side ? hc : hg;
  u16*  hT  = side ? hTc : hTg;
  const int r0 = (bid & 63) * 64;
  const int lrow = lane & 15, lhi = lane >> 4;

  f32x4 acc[4][2];
  const f32x4 z4 = {0.f,0.f,0.f,0.f};
  #pragma unroll
  for(int i=0;i<4;i++){ acc[i][0]=z4; acc[i][1]=z4; }

  const int r = t >> 3, c8 = t & 7;
  for(int k0 = 0; k0 < FIN; k0 += 64){
    const float* xp = x + (size_t)(r0 + r)*FIN + k0 + c8*8;
    float4 xa = *(const float4*)xp;
    float4 xb = *(const float4*)(xp + 4);
    short8 xv;
    xv[0]=(short)f2bf(xa.x); xv[1]=(short)f2bf(xa.y);
    xv[2]=(short)f2bf(xa.z); xv[3]=(short)f2bf(xa.w);
    xv[4]=(short)f2bf(xb.x); xv[5]=(short)f2bf(xb.y);
    xv[6]=(short)f2bf(xb.z); xv[7]=(short)f2bf(xb.w);
    int wbyte = r*128 + (((c8 ^ (r & 7)) & 7) << 4);
    *(short8*)(smem + wbyte) = xv;
    __syncthreads();
    #pragma unroll
    for(int ksub = 0; ksub < 2; ksub++){
      short8 b[2];
      #pragma unroll
      for(int nf=0; nf<2; nf++){
        int n = wid*32 + nf*16 + lrow;
        const float* wp = Wf + (size_t)n*FIN + k0 + ksub*32 + lhi*8;
        float4 wa = *(const float4*)wp;
        float4 wb = *(const float4*)(wp + 4);
        short8 bb;
        bb[0]=(short)f2bf(wa.x); bb[1]=(short)f2bf(wa.y);
        bb[2]=(short)f2bf(wa.z); bb[3]=(short)f2bf(wa.w);
        bb[4]=(short)f2bf(wb.x); bb[5]=(short)f2bf(wb.y);
        bb[6]=(short)f2bf(wb.z); bb[7]=(short)f2bf(wb.w);
        b[nf] = bb;
      }
      #pragma unroll
      for(int mf=0; mf<4; mf++){
        int row = mf*16 + lrow;
        int g = ksub*4 + lhi;
        short8 a = *(const short8*)(smem + row*128 + (((g ^ (row & 7)) & 7) << 4));
        #pragma unroll
        for(int nf=0; nf<2; nf++)
          acc[mf][nf] = __builtin_amdgcn_mfma_f32_16x16x32_bf16(a, b[nf], acc[mf][nf], 0,0,0);
      }
    }
    __syncthreads();
  }
  // write h (f32) and stage bf16 transpose in LDS
  #pragma unroll
  for(int mf=0; mf<4; mf++){
    #pragma unroll
    for(int nf=0; nf<2; nf++){
      int col = wid*32 + nf*16 + lrow;
      #pragma unroll
      for(int j=0;j<4;j++){
        int row = mf*16 + lhi*4 + j;
        float v = acc[mf][nf][j];
        h[(size_t)(r0+row)*DD + col] = v;
        int byte_ = col*128 + (((row*2) ^ ((col & 7)<<4)));
        *(u16*)(smem + byte_) = f2bf(v);
      }
    }
  }
  __syncthreads();
  { // tiled hT store (read-order layout): thread -> (n = t>>1 d-row, half)
    int n = t >> 1, half = t & 1;
    #pragma unroll
    for(int gi=0; gi<4; gi++){
      int g = half*4 + gi;
      int byte_ = n*128 + (((g ^ (n & 7)) & 7) << 4);
      short8 v = *(const short8*)(smem + byte_);
      int kcol = r0 + g*8;   // global k (node) index, 8-aligned
      size_t off = (size_t)(kcol>>5)*8192 + (size_t)(n>>4)*512
                 + ((kcol>>3)&3)*128 + (n&15)*8;
      *(short8*)(hT + off) = v;
    }
  }
}

// ---------------------------------------------------------------------------
// k_bitTT: transpose gc bits -> bitsT (both PLAIN layout, u64 load/store).
// One wave per 64x64-bit tile; 4096 tiles; 4 waves/block -> 1024 blocks.
// ---------------------------------------------------------------------------
__global__ __launch_bounds__(256) void k_bitTT(
    const u64* __restrict__ gcb, u64* __restrict__ bT)
{
  int t = threadIdx.x, wid = t>>6, lane = t&63;
  int id = blockIdx.x*4 + wid;          // 0..4095
  int G = id & 63, C = id >> 6;

  u64 x = gcb[(size_t)(64*G + lane)*64 + C];

  const u64 M1  = 0xAAAAAAAAAAAAAAAAull;
  const u64 M2  = 0xCCCCCCCCCCCCCCCCull;
  const u64 M4  = 0xF0F0F0F0F0F0F0F0ull;
  const u64 M8  = 0xFF00FF00FF00FF00ull;
  const u64 M16 = 0xFFFF0000FFFF0000ull;
  const u64 M32 = 0xFFFFFFFF00000000ull;
  #define TSTEP(S, M) { u64 y = shfl_xor64(x, S); \
    x = (lane & S) ? ((x & (M)) | ((y >> S) & ~(M))) \
                   : ((x & ~(M)) | ((y << S) & (M))); }
  TSTEP(32, M32) TSTEP(16, M16) TSTEP(8, M8)
  TSTEP(4,  M4)  TSTEP(2,  M2)  TSTEP(1, M1)
  #undef TSTEP

  bT[(size_t)(64*C + lane)*64 + G] = x;
}

// ---------------------------------------------------------------------------
// k_svec: per-row dot products with attention vectors + gate sigmoid.
// sbuf layout (each 4096 f32):
// 0 s1gg 1 s2gg 2 s1gc 3 s2cg 4 gam_g 5 s1cc 6 s2cc 7 s2gc 8 s1cg 9 gam_c
// ---------------------------------------------------------------------------
__global__ __launch_bounds__(256) void k_svec(
    const float* __restrict__ hg, const float* __restrict__ hc,
    const float* __restrict__ a_gg, const float* __restrict__ a_gc,
    const float* __restrict__ a_cc, const float* __restrict__ a_cg,
    const float* __restrict__ gw_g, const float* __restrict__ gb_g,
    const float* __restrict__ gw_c, const float* __restrict__ gb_c,
    float* __restrict__ sbuf)
{
  int t = threadIdx.x, wid = t>>6, lane = t&63;
  int idx = blockIdx.x * 4 + wid;          // 0..8191
  int side = idx >> 12;
  int row  = idx & 4095;
  const float* h = (side ? hc : hg) + (size_t)row*DD;
  const float* v0 = (side ? a_cc : a_gg);        // same-type s1 half
  const float* v1 = (side ? a_cc : a_gg) + DD;   // same-type s2 half
  const float* v2 = (side ? a_cg : a_gc);        // cross s1 (this node as src)
  const float* v3 = (side ? a_gc : a_cg) + DD;   // cross s2 (this node as dst)
  const float* gw = side ? gw_c : gw_g;
  float bias = (side ? gb_c : gb_g)[0];

  float4 hv = *(const float4*)(h + lane*4);
  float4 w0 = *(const float4*)(v0 + lane*4);
  float4 w1 = *(const float4*)(v1 + lane*4);
  float4 w2 = *(const float4*)(v2 + lane*4);
  float4 w3 = *(const float4*)(v3 + lane*4);
  float4 w4 = *(const float4*)(gw + lane*4);

  float d0 = hv.x*w0.x + hv.y*w0.y + hv.z*w0.z + hv.w*w0.w;
  float d1 = hv.x*w1.x + hv.y*w1.y + hv.z*w1.z + hv.w*w1.w;
  float d2 = hv.x*w2.x + hv.y*w2.y + hv.z*w2.z + hv.w*w2.w;
  float d3 = hv.x*w3.x + hv.y*w3.y + hv.z*w3.z + hv.w*w3.w;
  float d4 = hv.x*w4.x + hv.y*w4.y + hv.z*w4.z + hv.w*w4.w;
  #pragma unroll
  for(int s=1;s<64;s<<=1){
    d0 += __shfl_xor(d0, s); d1 += __shfl_xor(d1, s); d2 += __shfl_xor(d2, s);
    d3 += __shfl_xor(d3, s); d4 += __shfl_xor(d4, s);
  }
  if(lane == 0){
    float gam = 1.f/(1.f + __expf(-(d4 + bias)));
    if(side == 0){
      sbuf[0*4096+row]=d0; sbuf[1*4096+row]=d1; sbuf[2*4096+row]=d2;
      sbuf[3*4096+row]=d3; sbuf[4*4096+row]=gam;
    } else {
      sbuf[5*4096+row]=d0; sbuf[6*4096+row]=d1; sbuf[8*4096+row]=d2;
      sbuf[7*4096+row]=d3; sbuf[9*4096+row]=gam;
    }
  }
}

// ---------------------------------------------------------------------------
// k_gat: O^T = V^T * P^T, P generated in-register as the MFMA B-operand.
// grid (64 ng, 2 kc, 4 modes) x 256 thr (4 waves: 2 kh x 2 ng).
// A staged in LDS (global_load_lds, double-buffered, 32KB/step) and SHARED
// by the ng waves; conflict-free ds_read_b128 (fragment in lane-read order).
// One barrier/step; staging issued at step top so exp+MFMA hides L2 latency.
// Masks in XOR-swizzled LDS; s2 register-prefetched. 80KB LDS -> 2 blocks/CU.
// part stored as bf16 (halves store + epi-read traffic).
// ---------------------------------------------------------------------------
__global__ __launch_bounds__(256,2) void k_gat(
    const float* __restrict__ sbuf,
    const uint8_t* __restrict__ packbits, const uint8_t* __restrict__ bitsT,
    const u16* __restrict__ hTg, const u16* __restrict__ hTc,
    u16* __restrict__ part, float* __restrict__ Zpart)
{
  const int mode = blockIdx.z;
  const int kc   = blockIdx.y;
  const int nodebase = blockIdx.x * 64;
  const int kcbase   = kc * 2048;

  const float* s1; const float* s2; const uint8_t* bits; const u16* hT;
  if(mode == 0){ s1 = sbuf;        s2 = sbuf+4096;   bits = packbits;           hT = hTg; }
  else if(mode == 1){ s1 = sbuf+2*4096; s2 = sbuf+7*4096; bits = packbits+4194304; hT = hTc; }
  else if(mode == 2){ s1 = sbuf+5*4096; s2 = sbuf+6*4096; bits = packbits+2097152; hT = hTc; }
  else { s1 = sbuf+8*4096; s2 = sbuf+3*4096; bits = bitsT; hT = hTg; }

  const int t = threadIdx.x, wid = t>>6, lane = t&63, lrow = lane&15, lhi = lane>>4;
  const int kh = wid >> 1;        // k-half of the 2048 chunk
  const int ng_sub = wid & 1;     // 32-node group

  __shared__ __align__(16) char U[81920];
  char* A_lds  = U;               // [2 dbuf][2 kh][16KB]
  char* mask_l = U + 65536;       // [64 rows][256B], 16B-slot XOR-swizzled

  // ---- prologue: stage masks (16KB, swizzled 16B slots) ----
  {
    int row = t>>2, seg = t&3;
    const char* g = (const char*)bits + (size_t)(nodebase+row)*512 + kc*256 + seg*64;
    char* drow_ = mask_l + row*256;
    #pragma unroll
    for(int i=0;i<4;i++){
      int slot = seg*4 + i;
      *(ulonglong2*)(drow_ + (((slot ^ (row&7)))<<4)) = *(const ulonglong2*)(g + i*16);
    }
  }
  // ---- prologue: stage A step 0 into buf0 (each wave: its kh, its half) ----
  const char* hTb = (const char*)hT;
  {
    const char* g = hTb + ((size_t)kc*64 + kh*32 + 0)*16384 + ng_sub*8192 + lane*16;
    char* l = A_lds + 0*32768 + kh*16384 + ng_sub*8192;
    #pragma unroll
    for(int i=0;i<8;i++) gl16(g + i*1024, l + i*1024);
  }
  // ---- per-wave global max over FULL s2 (no cross-wave reduce needed) ----
  float mxv = -1e30f;
  #pragma unroll
  for(int i=0;i<16;i++){
    float4 v = *(const float4*)(s2 + lane*64 + i*4);
    mxv = fmaxf(mxv, fmaxf(fmaxf(v.x,v.y), fmaxf(v.z,v.w)));
  }
  #pragma unroll
  for(int sh=1; sh<64; sh<<=1) mxv = fmaxf(mxv, __shfl_xor(mxv, sh));
  const float maxs2 = mxv;

  const int wnode = nodebase + ng_sub*32;
  const float L2E = 1.4426950408889634f;
  float c1[2], c2[2], z[2];
  #pragma unroll
  for(int nf=0; nf<2; nf++){
    float s1v = s1[wnode + nf*16 + lrow];
    float m = lk(s1v + maxs2);
    c1[nf] = (s1v - m)*L2E;
    c2[nf] = (0.2f*s1v - m)*L2E;
    z[nf] = 0.f;
  }

  f32x4 acc[16][2];
  const f32x4 zz = {0.f,0.f,0.f,0.f};
  #pragma unroll
  for(int i=0;i<16;i++){ acc[i][0]=zz; acc[i][1]=zz; }

  const float* s2g = s2 + kcbase + kh*1024 + lhi*8;
  const char* mrow0 = mask_l + (ng_sub*32 + lrow)*256;
  const char* mrow1 = mask_l + (ng_sub*32 + 16 + lrow)*256;
  const int mx0 = (ng_sub*32 + lrow) & 7, mx1 = (ng_sub*32 + 16 + lrow) & 7;

  // s2 register prefetch for step 0
  float4 csA = *(const float4*)(s2g);
  float4 csB = *(const float4*)(s2g + 4);

  __syncthreads();   // masks + A step0 staged (vmcnt drained)

  // ---- main loop: 32 steps, 1 barrier/step ----
  #pragma unroll 1
  for(int s=0; s<32; s++){
    const int cur = s & 1;
    // stage step s+1 into buf^1 (hidden under this step's compute)
    if(s < 31){
      const char* g = hTb + ((size_t)kc*64 + kh*32 + s + 1)*16384 + ng_sub*8192 + lane*16;
      char* l = A_lds + (cur^1)*32768 + kh*16384 + ng_sub*8192;
      #pragma unroll
      for(int i=0;i<8;i++) gl16(g + i*1024, l + i*1024);
    }
    float4 sA = csA, sB = csB;
    if(s < 31){
      csA = *(const float4*)(s2g + (s+1)*32);
      csB = *(const float4*)(s2g + (s+1)*32 + 4);
    }
    float e1[8], e2[8];
    {
      float sv[8] = {sA.x,sA.y,sA.z,sA.w,sB.x,sB.y,sB.z,sB.w};
      #pragma unroll
      for(int j=0;j<8;j++){ e1[j] = sv[j]*L2E; e2[j] = sv[j]*(0.2f*L2E); }
    }
    // mask words (swizzled slot): wb = kh*128 + s*4
    const int slot = kh*8 + (s>>2), win = (s&3)*4;
    u32 mw0 = *(const u32*)(mrow0 + ((slot ^ mx0)<<4) + win);
    u32 mw1 = *(const u32*)(mrow1 + ((slot ^ mx1)<<4) + win);
    short8 b[2];
    #pragma unroll
    for(int nf=0; nf<2; nf++){
      u32 mw = nf ? mw1 : mw0;
      u32 w4[4];
      #pragma unroll
      for(int pr=0; pr<4; pr++){
        float bit0 = (float)((mw >> (lhi*8 + 2*pr  )) & 1u);
        float bit1 = (float)((mw >> (lhi*8 + 2*pr+1)) & 1u);
        float p0 = __builtin_amdgcn_exp2f(fmaxf(c1[nf]+e1[2*pr  ], c2[nf]+e2[2*pr  ])) * bit0;
        float p1 = __builtin_amdgcn_exp2f(fmaxf(c1[nf]+e1[2*pr+1], c2[nf]+e2[2*pr+1])) * bit1;
        z[nf] += p0 + p1;
        u32 q0 = __float_as_uint(p0) + 0x8000u;
        u32 q1 = __float_as_uint(p1) + 0x8000u;
        w4[pr] = (q1 & 0xFFFF0000u) | (q0 >> 16);
      }
      union{ u32 u[4]; short8 s8; } cv;
      cv.u[0]=w4[0]; cv.u[1]=w4[1]; cv.u[2]=w4[2]; cv.u[3]=w4[3];
      b[nf] = cv.s8;
    }
    // A from LDS (conflict-free: lane reads byte lane*16 of each 1KB frag)
    const char* Af = A_lds + cur*32768 + kh*16384 + lane*16;
    #pragma unroll
    for(int mf=0; mf<16; mf++){
      short8 a = *(const short8*)(Af + mf*1024);
      acc[mf][0] = __builtin_amdgcn_mfma_f32_16x16x32_bf16(a, b[0], acc[mf][0], 0,0,0);
      acc[mf][1] = __builtin_amdgcn_mfma_f32_16x16x32_bf16(a, b[1], acc[mf][1], 0,0,0);
    }
    __syncthreads();   // protects buf reuse + completes s+1 staging
  }

  // ---- Z: reduce across lhi, write per-(kc,kh) slot; k_epi sums 4 ----
  #pragma unroll
  for(int nf=0; nf<2; nf++){
    z[nf] += __shfl_xor(z[nf], 16);
    z[nf] += __shfl_xor(z[nf], 32);
  }
  if(lhi == 0){
    float* zp = Zpart + (size_t)(mode*4 + kc*2 + kh)*4096 + wnode;
    zp[lrow]      = z[0];
    zp[16 + lrow] = z[1];
  }

  // ---- kh-reduce via 32KB swizzled LDS (two 8-mf rounds), bf16 store ----
  __syncthreads();                 // loop done; A_lds free
  float* R = (float*)A_lds;        // [64 rows][128 f32], XOR-swizzled
  u16* po = part + ((size_t)(mode*2 + kc) << 20);
  #pragma unroll
  for(int half=0; half<2; half++){
    if(kh == 1){
      #pragma unroll
      for(int mf8=0; mf8<8; mf8++){
        #pragma unroll
        for(int nf=0; nf<2; nf++){
          int r = ng_sub*32 + nf*16 + lrow;
          int byte_ = r*512 + ((mf8*64 + lhi*16) ^ ((r&7)<<4));
          *(f32x4*)((char*)R + byte_) = acc[half*8 + mf8][nf];
        }
      }
    }
    __syncthreads();
    if(kh == 0){
      #pragma unroll
      for(int mf8=0; mf8<8; mf8++){
        #pragma unroll
        for(int nf=0; nf<2; nf++){
          int r = ng_sub*32 + nf*16 + lrow;
          int byte_ = r*512 + ((mf8*64 + lhi*16) ^ ((r&7)<<4));
          f32x4 o = *(const f32x4*)((const char*)R + byte_);
          o = o + acc[half*8 + mf8][nf];
          int node = nodebase + r;
          *(u64*)(po + (size_t)node*256 + (half*8+mf8)*16 + lhi*4) = pack4bf(o);
        }
      }
    }
    __syncthreads();
  }
}

// ---------------------------------------------------------------------------
// k_epi: out = leaky(h + sum(A)/za + gamma*sum(B)/zb), fused kc/kh-reduce.
// part is bf16.
// ---------------------------------------------------------------------------
__global__ __launch_bounds__(256) void k_epi(
    const float* __restrict__ hg, const float* __restrict__ hc,
    const u16* __restrict__ part, const float* __restrict__ Zpart,
    const float* __restrict__ sbuf, float* __restrict__ out)
{
  int idx = blockIdx.x*256 + threadIdx.x;   // 0..524287
  int fid = idx*4;
  int side = fid >> 20;
  int l = fid & 1048575;
  int node = l >> 8;
  int modeA = side ? 2 : 0, modeB = side ? 3 : 1;
  const float* h = side ? hc : hg;
  float gam = sbuf[(side ? 9 : 4)*4096 + node];
  float za = Zpart[(size_t)(modeA*4+0)*4096 + node] + Zpart[(size_t)(modeA*4+1)*4096 + node]
           + Zpart[(size_t)(modeA*4+2)*4096 + node] + Zpart[(size_t)(modeA*4+3)*4096 + node];
  float zb = Zpart[(size_t)(modeB*4+0)*4096 + node] + Zpart[(size_t)(modeB*4+1)*4096 + node]
           + Zpart[(size_t)(modeB*4+2)*4096 + node] + Zpart[(size_t)(modeB*4+3)*4096 + node];
  float rza = 1.f / fmaxf(za, 1e-30f);
  float rzb = 1.f / fmaxf(zb, 1e-30f);
  ushort4 a0 = *(const ushort4*)(part + ((size_t)(modeA*2  )<<20) + l);
  ushort4 a1 = *(const ushort4*)(part + ((size_t)(modeA*2+1)<<20) + l);
  ushort4 b0 = *(const ushort4*)(part + ((size_t)(modeB*2  )<<20) + l);
  ushort4 b1 = *(const ushort4*)(part + ((size_t)(modeB*2+1)<<20) + l);
  float4 h4 = *(const float4*)(h + l);
  float4 o;
  o.x = lk(h4.x + (bf2f(a0.x)+bf2f(a1.x))*rza + gam*(bf2f(b0.x)+bf2f(b1.x))*rzb);
  o.y = lk(h4.y + (bf2f(a0.y)+bf2f(a1.y))*rza + gam*(bf2f(b0.y)+bf2f(b1.y))*rzb);
  o.z = lk(h4.z + (bf2f(a0.z)+bf2f(a1.z))*rza + gam*(bf2f(b0.z)+bf2f(b1.z))*rzb);
  o.w = lk(h4.w + (bf2f(a0.w)+bf2f(a1.w))*rza + gam*(bf2f(b0.w)+bf2f(b1.w))*rzb);
  *(float4*)(out + fid) = o;
}

// ---------------------------------------------------------------------------
extern "C" void kernel_launch(void* const* d_in, const int* in_sizes, int n_in,
                              void* d_out, int out_size, void* d_ws, size_t ws_size,
                              hipStream_t stream)
{
  const float* gene_x   = (const float*)d_in[0];
  const float* cell_x   = (const float*)d_in[1];
  const float* gene_adj = (const float*)d_in[2];
  const float* cell_adj = (const float*)d_in[3];
  const float* gc_adj   = (const float*)d_in[4];
  const float* Wg       = (const float*)d_in[5];
  const float* Wc       = (const float*)d_in[6];
  const float* a_gg     = (const float*)d_in[7];
  const float* a_gc     = (const float*)d_in[8];
  const float* a_cc     = (const float*)d_in[9];
  const float* a_cg     = (const float*)d_in[10];
  const float* gw_g     = (const float*)d_in[11];
  const float* gb_g     = (const float*)d_in[12];
  const float* gw_c     = (const float*)d_in[13];
  const float* gb_c     = (const float*)d_in[14];

  char* ws = (char*)d_ws;
  float* hg   = (float*)(ws);                    // 4MB
  float* hc   = (float*)(ws + (4u<<20));         // 4MB
  u16*   hTg  = (u16*)  (ws + (8u<<20));         // 2MB (tiled)
  u16*   hTc  = (u16*)  (ws + (10u<<20));        // 2MB (tiled)
  float* sbuf = (float*)(ws + (12u<<20));        // 160KB
  float* Zpart= (float*)(ws + (12u<<20) + (512u<<10)); // 256KB (16 x 4096 f32)
  uint8_t* bitsT = (uint8_t*)(ws + (13u<<20));   // 2MB
  u16*   part = (u16*)  (ws + (17u<<20));        // 16MB bf16: [mode][kc][node][d]
  u64*   packbits = (u64*)(ws + (49u<<20));      // 6MB: gene, cell, gc; ends 55MB

  k_front<<<dim3(384), 512, 0, stream>>>(gene_adj, cell_adj, gc_adj, packbits,
                                         gene_x, cell_x, Wg, Wc,
                                         hg, hc, hTg, hTc);
  k_bitTT<<<dim3(1024), 256, 0, stream>>>(packbits + 524288, (u64*)bitsT);
  k_svec<<<dim3(2048), 256, 0, stream>>>(hg, hc, a_gg, a_gc, a_cc, a_cg,
                                         gw_g, gb_g, gw_c, gb_c, sbuf);
  k_gat<<<dim3(64,2,4), 256, 0, stream>>>(sbuf, (const uint8_t*)packbits,
                                          bitsT, hTg, hTc, part, Zpart);
  k_epi<<<dim3(2048), 256, 0, stream>>>(hg, hc, part, Zpart, sbuf, (float*)d_out);
}